// Round 3
// baseline (1106.574 us; speedup 1.0000x reference)
//
#include <hip/hip_runtime.h>
#include <hip/hip_bf16.h>
#include <cstdint>
#include <cstddef>

// Problem constants
#define NB 64      // batch
#define NT 256     // time steps
#define NL 64      // links
#define NH 128     // hidden
#define NN 16384   // nodes = NB*NT
#define NE 524288  // edges
#define NG 512     // 4*NH gates
#define NOUT 768   // 12*NL

// ---------------- small prep kernels ----------------

// Wt[n][k] = W[k][n], W is [K, Nout] row-major
__global__ __launch_bounds__(256) void k_transpose(const float* __restrict__ W,
                                                   float* __restrict__ Wt,
                                                   int K, int Nout) {
  int i = blockIdx.x * 256 + threadIdx.x;
  if (i < K * Nout) {
    int k = i / Nout, n = i % Nout;
    Wt[n * K + k] = W[i];
  }
}

// dvec[j] = sum_m dist[m] * W0[(64+m)*128 + j]   (128 blocks, one per j)
__global__ __launch_bounds__(256) void k_dvec(const float* __restrict__ dist,
                                              const float* __restrict__ W0,
                                              float* __restrict__ dvec) {
  __shared__ float red[256];
  int j = blockIdx.x;
  int t = threadIdx.x;
  float acc = 0.f;
  for (int m = t; m < 4096; m += 256)
    acc += dist[m] * W0[(size_t)(64 + m) * 128 + j];
  red[t] = acc;
  __syncthreads();
  for (int off = 128; off > 0; off >>= 1) {
    if (t < off) red[t] += red[t + off];
    __syncthreads();
  }
  if (t == 0) dvec[j] = red[0];
}

__global__ __launch_bounds__(256) void k_count(const int* __restrict__ dst,
                                               int* __restrict__ counts) {
  int i = blockIdx.x * 256 + threadIdx.x;
  atomicAdd(&counts[dst[i]], 1);
}

__global__ __launch_bounds__(256) void k_dinv(const int* __restrict__ counts,
                                              float* __restrict__ dinv) {
  int n = blockIdx.x * 256 + threadIdx.x;
  dinv[n] = rsqrtf((float)counts[n] + 1.0f);
}

// exclusive scan of counts[16384] -> rowstart[16385]; single block of 1024
__global__ __launch_bounds__(1024) void k_scan(const int* __restrict__ counts,
                                               int* __restrict__ rowstart) {
  __shared__ int part[1024];
  int t = threadIdx.x;
  int base = t * 16;
  int local[16];
  int s = 0;
#pragma unroll
  for (int i = 0; i < 16; i++) { local[i] = s; s += counts[base + i]; }
  part[t] = s;
  __syncthreads();
  for (int off = 1; off < 1024; off <<= 1) {
    int v = (t >= off) ? part[t - off] : 0;
    __syncthreads();
    part[t] += v;
    __syncthreads();
  }
  int prefix = (t == 0) ? 0 : part[t - 1];
#pragma unroll
  for (int i = 0; i < 16; i++) rowstart[base + i] = prefix + local[i];
  if (t == 1023) rowstart[16384] = part[1023];
}

__global__ __launch_bounds__(256) void k_fill(const int* __restrict__ src,
                                              const int* __restrict__ dst,
                                              const int* __restrict__ rowstart,
                                              int* __restrict__ fill,
                                              const float* __restrict__ dinv,
                                              int2* __restrict__ csr) {
  int e = blockIdx.x * 256 + threadIdx.x;
  int sN = src[e], dN = dst[e];
  int pos = rowstart[dN] + atomicAdd(&fill[dN], 1);
  csr[pos] = make_int2(sN, __float_as_int(dinv[sN] * dinv[dN]));
}

// ---------------- GEMM: C[M,Nn] = A[M,K] * B[Nn,K]^T (+bias0+bias1) ----------------
// grid (M/64, Nn/64), block 256. K = 64 or 128.
// PERMC: store col' = (col&127)*4 + (col>>7)  (gate-interleaved layout for LSTM pre)
template <int K, bool RELU, bool PERMC = false>
__global__ __launch_bounds__(256) void k_gemm_abt(const float* __restrict__ A,
                                                  const float* __restrict__ Bm,
                                                  const float* __restrict__ bias0,
                                                  const float* __restrict__ bias1,
                                                  float* __restrict__ C, int Nn) {
  __shared__ float As[64][K + 1];
  __shared__ float Bs[64][K + 1];
  const int tid = threadIdx.x;
  const int bm = blockIdx.x, bn = blockIdx.y;
  const int VPR = K / 4;  // float4 per row
  for (int i = tid; i < 64 * VPR; i += 256) {
    int r = i / VPR, v = (i % VPR) * 4;
    float4 q = *(const float4*)(A + (size_t)(bm * 64 + r) * K + v);
    As[r][v] = q.x; As[r][v + 1] = q.y; As[r][v + 2] = q.z; As[r][v + 3] = q.w;
  }
  for (int i = tid; i < 64 * VPR; i += 256) {
    int r = i / VPR, v = (i % VPR) * 4;
    float4 q = *(const float4*)(Bm + (size_t)(bn * 64 + r) * K + v);
    Bs[r][v] = q.x; Bs[r][v + 1] = q.y; Bs[r][v + 2] = q.z; Bs[r][v + 3] = q.w;
  }
  __syncthreads();
  const int tr = (tid >> 4) << 2;   // output rows tr..tr+3
  const int tc = (tid & 15) << 2;   // output cols tc..tc+3
  float acc[4][4] = {};
#pragma unroll 4
  for (int k = 0; k < K; k++) {
    float a0 = As[tr + 0][k], a1 = As[tr + 1][k], a2 = As[tr + 2][k], a3 = As[tr + 3][k];
    float b0 = Bs[tc + 0][k], b1 = Bs[tc + 1][k], b2 = Bs[tc + 2][k], b3 = Bs[tc + 3][k];
    acc[0][0] += a0 * b0; acc[0][1] += a0 * b1; acc[0][2] += a0 * b2; acc[0][3] += a0 * b3;
    acc[1][0] += a1 * b0; acc[1][1] += a1 * b1; acc[1][2] += a1 * b2; acc[1][3] += a1 * b3;
    acc[2][0] += a2 * b0; acc[2][1] += a2 * b1; acc[2][2] += a2 * b2; acc[2][3] += a2 * b3;
    acc[3][0] += a3 * b0; acc[3][1] += a3 * b1; acc[3][2] += a3 * b2; acc[3][3] += a3 * b3;
  }
#pragma unroll
  for (int i2 = 0; i2 < 4; i2++) {
    int row = bm * 64 + tr + i2;
#pragma unroll
    for (int j2 = 0; j2 < 4; j2++) {
      int col = bn * 64 + tc + j2;
      float v = acc[i2][j2];
      if (bias0) v += bias0[col];
      if (bias1) v += bias1[col];
      if (RELU) v = fmaxf(v, 0.f);
      int colw = PERMC ? ((col & 127) * 4 + (col >> 7)) : col;
      C[(size_t)row * Nn + colw] = v;
    }
  }
}

// ---------------- GCN aggregation (float2 lanes, packed CSR) ----------------
__global__ __launch_bounds__(256) void k_agg(const float* __restrict__ h,
                                             const int* __restrict__ rowstart,
                                             const int2* __restrict__ csr,
                                             const float* __restrict__ dinv,
                                             const float* __restrict__ bias,
                                             float* __restrict__ out) {
  int node = blockIdx.x * 4 + (threadIdx.x >> 6);
  int lane = threadIdx.x & 63;
  int s = rowstart[node], e = rowstart[node + 1];
  const float2* h2 = (const float2*)h;
  float ax = 0.f, ay = 0.f;
  int p = s;
  for (; p + 1 < e; p += 2) {
    int2 pk0 = csr[p];
    int2 pk1 = csr[p + 1];
    float2 hv0 = h2[(size_t)pk0.x * 64 + lane];
    float2 hv1 = h2[(size_t)pk1.x * 64 + lane];
    float w0 = __int_as_float(pk0.y);
    float w1 = __int_as_float(pk1.y);
    ax = fmaf(hv0.x, w0, ax); ay = fmaf(hv0.y, w0, ay);
    ax = fmaf(hv1.x, w1, ax); ay = fmaf(hv1.y, w1, ay);
  }
  if (p < e) {
    int2 pk0 = csr[p];
    float2 hv0 = h2[(size_t)pk0.x * 64 + lane];
    float w0 = __int_as_float(pk0.y);
    ax = fmaf(hv0.x, w0, ax); ay = fmaf(hv0.y, w0, ay);
  }
  float di = dinv[node];
  float sw = di * di;
  float2 hs = h2[(size_t)node * 64 + lane];
  float2 bv = ((const float2*)bias)[lane];
  ax = fmaf(hs.x, sw, ax) + bv.x;
  ay = fmaf(hs.y, sw, ay) + bv.y;
  float2 o;
  o.x = fmaxf(ax, 0.f);
  o.y = fmaxf(ay, 0.f);
  ((float2*)out)[(size_t)node * 64 + lane] = o;
}

// ---------------- LSTM recurrence v3: oct-per-unit, 1024 threads ----------------
// 1024 threads = 128 octs. Oct u owns unit u; lane e of oct covers k in [16e,16e+16)
// for ALL 4 gates (16 float4 weights = 64 VGPRs). Reduce over 8 lanes:
// quad_perm xor1 + xor2 (DPP) + xor4 (ds_swizzle). h in skewed LDS
// (group stride 20 floats -> the 8 e-lanes hit disjoint bank groups).
// pre is permuted P'[n][u*4+g]; lane e<4 folds pre of gate e into its accumulator.

template <int CTRL>
__device__ __forceinline__ float dppadd(float x) {
  int r = __builtin_amdgcn_update_dpp(0, __float_as_int(x), CTRL, 0xF, 0xF, true);
  return x + __int_as_float(r);
}
__device__ __forceinline__ float swzadd4(float x) {
  int r = __builtin_amdgcn_ds_swizzle(__float_as_int(x), 0x101F);  // xor lane^4
  return x + __int_as_float(r);
}

__device__ __forceinline__ float sigf(float x) {
  return 1.f / (1.f + __expf(-x));
}
__device__ __forceinline__ float tanhf_fast(float x) {
  return 1.f - 2.f / (__expf(2.f * x) + 1.f);
}

typedef float f4v __attribute__((ext_vector_type(4)));

template <bool LAST_ONLY>
__global__ __launch_bounds__(1024, 4) void k_lstm3(const float* __restrict__ pre,
                                                   const float* __restrict__ Whh,
                                                   float* __restrict__ yout) {
  __shared__ float hbuf[2][160];  // 8 groups of 16 floats, stride 20 (skewed)
  const int tid = threadIdx.x;
  const int b = blockIdx.x;
  const int e = tid & 7;   // k-slice selector (16 floats each)
  const int u = tid >> 3;  // hidden unit 0..127

  // weights: Wv[g][j] = Whh[g*128+u][16e + 4j .. +3]
  f4v Wv[4][4];
#pragma unroll
  for (int g = 0; g < 4; g++)
#pragma unroll
    for (int j = 0; j < 4; j++)
      Wv[g][j] = *(const f4v*)(Whh + (size_t)(g * 128 + u) * 128 + e * 16 + j * 4);

  // init h=0
  if (tid < 160) hbuf[0][tid] = 0.f;
  float cs = 0.f;
  const float* preb = pre + (size_t)b * NT * NG + (u * 4 + (e & 3));
  float pcur = preb[0];
  const int rdoff = e * 20;                       // float offset of my k-group
  const int wroff = (u >> 4) * 20 + (u & 15);     // where h[u] lives
  float* ybase = LAST_ONLY ? (yout + (size_t)b * NH + u)
                           : (yout + (size_t)b * NT * NH + u);
  __syncthreads();

#define LSTM_STEP(CUR, NXT, T)                                                 \
  {                                                                            \
    int tn = (T) + 1; if (tn > NT - 1) tn = NT - 1;                            \
    float pnext = preb[(size_t)tn * NG];                                       \
    const float* hr = &hbuf[CUR][rdoff];                                       \
    f4v h0 = *(const f4v*)(hr);                                                \
    f4v h1 = *(const f4v*)(hr + 4);                                            \
    f4v h2 = *(const f4v*)(hr + 8);                                            \
    f4v h3 = *(const f4v*)(hr + 12);                                           \
    f4v a0 = {0.f, 0.f, 0.f, 0.f}, a1 = a0, a2 = a0, a3 = a0;                  \
    a0 = __builtin_elementwise_fma(Wv[0][0], h0, a0);                          \
    a1 = __builtin_elementwise_fma(Wv[1][0], h0, a1);                          \
    a2 = __builtin_elementwise_fma(Wv[2][0], h0, a2);                          \
    a3 = __builtin_elementwise_fma(Wv[3][0], h0, a3);                          \
    a0 = __builtin_elementwise_fma(Wv[0][1], h1, a0);                          \
    a1 = __builtin_elementwise_fma(Wv[1][1], h1, a1);                          \
    a2 = __builtin_elementwise_fma(Wv[2][1], h1, a2);                          \
    a3 = __builtin_elementwise_fma(Wv[3][1], h1, a3);                          \
    a0 = __builtin_elementwise_fma(Wv[0][2], h2, a0);                          \
    a1 = __builtin_elementwise_fma(Wv[1][2], h2, a1);                          \
    a2 = __builtin_elementwise_fma(Wv[2][2], h2, a2);                          \
    a3 = __builtin_elementwise_fma(Wv[3][2], h2, a3);                          \
    a0 = __builtin_elementwise_fma(Wv[0][3], h3, a0);                          \
    a1 = __builtin_elementwise_fma(Wv[1][3], h3, a1);                          \
    a2 = __builtin_elementwise_fma(Wv[2][3], h3, a2);                          \
    a3 = __builtin_elementwise_fma(Wv[3][3], h3, a3);                          \
    float s0 = (a0.x + a0.y) + (a0.z + a0.w) + ((e == 0) ? pcur : 0.f);        \
    float s1 = (a1.x + a1.y) + (a1.z + a1.w) + ((e == 1) ? pcur : 0.f);        \
    float s2 = (a2.x + a2.y) + (a2.z + a2.w) + ((e == 2) ? pcur : 0.f);        \
    float s3 = (a3.x + a3.y) + (a3.z + a3.w) + ((e == 3) ? pcur : 0.f);        \
    s0 = dppadd<0xB1>(s0); s0 = dppadd<0x4E>(s0); s0 = swzadd4(s0);            \
    s1 = dppadd<0xB1>(s1); s1 = dppadd<0x4E>(s1); s1 = swzadd4(s1);            \
    s2 = dppadd<0xB1>(s2); s2 = dppadd<0x4E>(s2); s2 = swzadd4(s2);            \
    s3 = dppadd<0xB1>(s3); s3 = dppadd<0x4E>(s3); s3 = swzadd4(s3);            \
    float si = sigf(s0), sf = sigf(s1), tg = tanhf_fast(s2), so = sigf(s3);    \
    cs = sf * cs + si * tg;                                                    \
    float hnew = so * tanhf_fast(cs);                                          \
    if (e == 0) hbuf[NXT][wroff] = hnew;                                       \
    if (!LAST_ONLY) {                                                          \
      if (e == 1) ybase[(size_t)(T) * NH] = hnew;                              \
    } else if ((T) == NT - 1) {                                                \
      if (e == 1) *ybase = hnew;                                               \
    }                                                                          \
    pcur = pnext;                                                              \
    __syncthreads();                                                           \
  }

  for (int t = 0; t < NT; t += 2) {
    LSTM_STEP(0, 1, t);
    LSTM_STEP(1, 0, t + 1);
  }
#undef LSTM_STEP
}

// ---------------- host ----------------

extern "C" void kernel_launch(void* const* d_in, const int* in_sizes, int n_in,
                              void* d_out, int out_size, void* d_ws, size_t ws_size,
                              hipStream_t stream) {
  const float* x    = (const float*)d_in[0];   // [64,256,64] -> [16384,64]
  const float* dist = (const float*)d_in[1];   // [64,64]
  const int*   ei   = (const int*)d_in[2];     // [2, 524288]
  const float* W0   = (const float*)d_in[3];   // [4160,128]
  const float* b0   = (const float*)d_in[4];
  const float* W1   = (const float*)d_in[5];   // [128,128]
  const float* b1   = (const float*)d_in[6];
  const float* W2   = (const float*)d_in[7];
  const float* b2   = (const float*)d_in[8];
  const float* Wih0 = (const float*)d_in[9];   // [512,128]
  const float* Whh0 = (const float*)d_in[10];  // [512,128]
  const float* bih0 = (const float*)d_in[11];
  const float* bhh0 = (const float*)d_in[12];
  const float* Wih1 = (const float*)d_in[13];
  const float* Whh1 = (const float*)d_in[14];
  const float* bih1 = (const float*)d_in[15];
  const float* bhh1 = (const float*)d_in[16];
  const float* fcW  = (const float*)d_in[17];  // [768,128]
  const float* fcb  = (const float*)d_in[18];
  float* out = (float*)d_out;

  char* ws = (char*)d_ws;
  size_t off = 0;
  auto alloc = [&](size_t bytes) -> void* {
    void* p = ws + off;
    off += (bytes + 255) & ~(size_t)255;
    return p;
  };
  float* bufA     = (float*)alloc((size_t)NN * 128 * 4);
  float* bufB     = (float*)alloc((size_t)NN * 128 * 4);
  float* pre      = (float*)alloc((size_t)NN * 512 * 4);
  int2*  csr      = (int2*)alloc((size_t)NE * 8);
  int*   counts   = (int*)alloc((size_t)NN * 4);
  int*   fillc    = (int*)alloc((size_t)NN * 4);
  int*   rowstart = (int*)alloc((size_t)(NN + 1) * 4);
  float* dinv     = (float*)alloc((size_t)NN * 4);
  float* dvec     = (float*)alloc(128 * 4);
  float* hlast    = (float*)alloc(64 * 128 * 4);
  float* wt0      = (float*)alloc(128 * 64 * 4);
  float* wt1      = (float*)alloc(128 * 128 * 4);
  float* wt2      = (float*)alloc(128 * 128 * 4);
  (void)ws_size; (void)in_sizes; (void)n_in; (void)out_size;

  const int* srcIdx = ei;
  const int* dstIdx = ei + NE;

  hipMemsetAsync(counts, 0, (size_t)NN * 4, stream);
  hipMemsetAsync(fillc, 0, (size_t)NN * 4, stream);

  // weight transposes + distance vector
  k_transpose<<<(64 * 128 + 255) / 256, 256, 0, stream>>>(W0, wt0, 64, 128);
  k_transpose<<<(128 * 128 + 255) / 256, 256, 0, stream>>>(W1, wt1, 128, 128);
  k_transpose<<<(128 * 128 + 255) / 256, 256, 0, stream>>>(W2, wt2, 128, 128);
  k_dvec<<<128, 256, 0, stream>>>(dist, W0, dvec);

  // CSR build (reused by all 3 GCN layers)
  k_count<<<NE / 256, 256, 0, stream>>>(dstIdx, counts);
  k_scan<<<1, 1024, 0, stream>>>(counts, rowstart);
  k_dinv<<<NN / 256, 256, 0, stream>>>(counts, dinv);
  k_fill<<<NE / 256, 256, 0, stream>>>(srcIdx, dstIdx, rowstart, fillc, dinv, csr);

  // GCN layer 0: h0 = x @ W0a^T + dvec  (bias/relu happen after aggregation)
  dim3 gH(NN / 64, 128 / 64);
  k_gemm_abt<64, false><<<gH, 256, 0, stream>>>(x, wt0, dvec, nullptr, bufB, 128);
  k_agg<<<NN / 4, 256, 0, stream>>>(bufB, rowstart, csr, dinv, b0, bufA);
  // GCN layer 1
  k_gemm_abt<128, false><<<gH, 256, 0, stream>>>(bufA, wt1, nullptr, nullptr, bufB, 128);
  k_agg<<<NN / 4, 256, 0, stream>>>(bufB, rowstart, csr, dinv, b1, bufA);
  // GCN layer 2
  k_gemm_abt<128, false><<<gH, 256, 0, stream>>>(bufA, wt2, nullptr, nullptr, bufB, 128);
  k_agg<<<NN / 4, 256, 0, stream>>>(bufB, rowstart, csr, dinv, b2, bufA);

  // LSTM layer 0: pre (permuted) = feat @ Wih0^T + bih0 + bhh0 ; recurrence -> y1 (bufB)
  dim3 gP(NN / 64, 512 / 64);
  k_gemm_abt<128, false, true><<<gP, 256, 0, stream>>>(bufA, Wih0, bih0, bhh0, pre, 512);
  k_lstm3<false><<<64, 1024, 0, stream>>>(pre, Whh0, bufB);
  // LSTM layer 1
  k_gemm_abt<128, false, true><<<gP, 256, 0, stream>>>(bufB, Wih1, bih1, bhh1, pre, 512);
  k_lstm3<true><<<64, 1024, 0, stream>>>(pre, Whh1, hlast);

  // FC: out[64,768] = hlast @ fcW^T + fcb
  dim3 gF(1, NOUT / 64);
  k_gemm_abt<128, false><<<gF, 256, 0, stream>>>(hlast, fcW, fcb, nullptr, out, NOUT);
}

// Round 4
// 1104.339 us; speedup vs baseline: 1.0020x; 1.0020x over previous
//
#include <hip/hip_runtime.h>
#include <hip/hip_bf16.h>
#include <cstdint>
#include <cstddef>

// Problem constants
#define NB 64      // batch
#define NT 256     // time steps
#define NL 64      // links
#define NH 128     // hidden
#define NN 16384   // nodes = NB*NT
#define NE 524288  // edges
#define NG 512     // 4*NH gates
#define NOUT 768   // 12*NL

// ---------------- small prep kernels ----------------

// Wt[n][k] = W[k][n], W is [K, Nout] row-major
__global__ __launch_bounds__(256) void k_transpose(const float* __restrict__ W,
                                                   float* __restrict__ Wt,
                                                   int K, int Nout) {
  int i = blockIdx.x * 256 + threadIdx.x;
  if (i < K * Nout) {
    int k = i / Nout, n = i % Nout;
    Wt[n * K + k] = W[i];
  }
}

// dvec[j] = sum_m dist[m] * W0[(64+m)*128 + j]   (128 blocks, one per j)
__global__ __launch_bounds__(256) void k_dvec(const float* __restrict__ dist,
                                              const float* __restrict__ W0,
                                              float* __restrict__ dvec) {
  __shared__ float red[256];
  int j = blockIdx.x;
  int t = threadIdx.x;
  float acc = 0.f;
  for (int m = t; m < 4096; m += 256)
    acc += dist[m] * W0[(size_t)(64 + m) * 128 + j];
  red[t] = acc;
  __syncthreads();
  for (int off = 128; off > 0; off >>= 1) {
    if (t < off) red[t] += red[t + off];
    __syncthreads();
  }
  if (t == 0) dvec[j] = red[0];
}

__global__ __launch_bounds__(256) void k_count(const int* __restrict__ dst,
                                               int* __restrict__ counts) {
  int i = blockIdx.x * 256 + threadIdx.x;
  atomicAdd(&counts[dst[i]], 1);
}

__global__ __launch_bounds__(256) void k_dinv(const int* __restrict__ counts,
                                              float* __restrict__ dinv) {
  int n = blockIdx.x * 256 + threadIdx.x;
  dinv[n] = rsqrtf((float)counts[n] + 1.0f);
}

// exclusive scan of counts[16384] -> rowstart[16385]; single block of 1024
__global__ __launch_bounds__(1024) void k_scan(const int* __restrict__ counts,
                                               int* __restrict__ rowstart) {
  __shared__ int part[1024];
  int t = threadIdx.x;
  int base = t * 16;
  int local[16];
  int s = 0;
#pragma unroll
  for (int i = 0; i < 16; i++) { local[i] = s; s += counts[base + i]; }
  part[t] = s;
  __syncthreads();
  for (int off = 1; off < 1024; off <<= 1) {
    int v = (t >= off) ? part[t - off] : 0;
    __syncthreads();
    part[t] += v;
    __syncthreads();
  }
  int prefix = (t == 0) ? 0 : part[t - 1];
#pragma unroll
  for (int i = 0; i < 16; i++) rowstart[base + i] = prefix + local[i];
  if (t == 1023) rowstart[16384] = part[1023];
}

__global__ __launch_bounds__(256) void k_fill(const int* __restrict__ src,
                                              const int* __restrict__ dst,
                                              const int* __restrict__ rowstart,
                                              int* __restrict__ fill,
                                              const float* __restrict__ dinv,
                                              int2* __restrict__ csr) {
  int e = blockIdx.x * 256 + threadIdx.x;
  int sN = src[e], dN = dst[e];
  int pos = rowstart[dN] + atomicAdd(&fill[dN], 1);
  csr[pos] = make_int2(sN, __float_as_int(dinv[sN] * dinv[dN]));
}

// ---------------- GEMM: C[M,Nn] = A[M,K] * B[Nn,K]^T (+bias0+bias1) ----------------
// grid (M/64, Nn/64), block 256. K = 64 or 128.
// PERMC: store col' = (col&127)*4 + (col>>7)  (gate-interleaved layout for LSTM pre)
template <int K, bool RELU, bool PERMC = false>
__global__ __launch_bounds__(256) void k_gemm_abt(const float* __restrict__ A,
                                                  const float* __restrict__ Bm,
                                                  const float* __restrict__ bias0,
                                                  const float* __restrict__ bias1,
                                                  float* __restrict__ C, int Nn) {
  __shared__ float As[64][K + 1];
  __shared__ float Bs[64][K + 1];
  const int tid = threadIdx.x;
  const int bm = blockIdx.x, bn = blockIdx.y;
  const int VPR = K / 4;  // float4 per row
  for (int i = tid; i < 64 * VPR; i += 256) {
    int r = i / VPR, v = (i % VPR) * 4;
    float4 q = *(const float4*)(A + (size_t)(bm * 64 + r) * K + v);
    As[r][v] = q.x; As[r][v + 1] = q.y; As[r][v + 2] = q.z; As[r][v + 3] = q.w;
  }
  for (int i = tid; i < 64 * VPR; i += 256) {
    int r = i / VPR, v = (i % VPR) * 4;
    float4 q = *(const float4*)(Bm + (size_t)(bn * 64 + r) * K + v);
    Bs[r][v] = q.x; Bs[r][v + 1] = q.y; Bs[r][v + 2] = q.z; Bs[r][v + 3] = q.w;
  }
  __syncthreads();
  const int tr = (tid >> 4) << 2;   // output rows tr..tr+3
  const int tc = (tid & 15) << 2;   // output cols tc..tc+3
  float acc[4][4] = {};
#pragma unroll 4
  for (int k = 0; k < K; k++) {
    float a0 = As[tr + 0][k], a1 = As[tr + 1][k], a2 = As[tr + 2][k], a3 = As[tr + 3][k];
    float b0 = Bs[tc + 0][k], b1 = Bs[tc + 1][k], b2 = Bs[tc + 2][k], b3 = Bs[tc + 3][k];
    acc[0][0] += a0 * b0; acc[0][1] += a0 * b1; acc[0][2] += a0 * b2; acc[0][3] += a0 * b3;
    acc[1][0] += a1 * b0; acc[1][1] += a1 * b1; acc[1][2] += a1 * b2; acc[1][3] += a1 * b3;
    acc[2][0] += a2 * b0; acc[2][1] += a2 * b1; acc[2][2] += a2 * b2; acc[2][3] += a2 * b3;
    acc[3][0] += a3 * b0; acc[3][1] += a3 * b1; acc[3][2] += a3 * b2; acc[3][3] += a3 * b3;
  }
#pragma unroll
  for (int i2 = 0; i2 < 4; i2++) {
    int row = bm * 64 + tr + i2;
#pragma unroll
    for (int j2 = 0; j2 < 4; j2++) {
      int col = bn * 64 + tc + j2;
      float v = acc[i2][j2];
      if (bias0) v += bias0[col];
      if (bias1) v += bias1[col];
      if (RELU) v = fmaxf(v, 0.f);
      int colw = PERMC ? ((col & 127) * 4 + (col >> 7)) : col;
      C[(size_t)row * Nn + colw] = v;
    }
  }
}

// ---------------- GCN aggregation (float2 lanes, packed CSR) ----------------
__global__ __launch_bounds__(256) void k_agg(const float* __restrict__ h,
                                             const int* __restrict__ rowstart,
                                             const int2* __restrict__ csr,
                                             const float* __restrict__ dinv,
                                             const float* __restrict__ bias,
                                             float* __restrict__ out) {
  int node = blockIdx.x * 4 + (threadIdx.x >> 6);
  int lane = threadIdx.x & 63;
  int s = rowstart[node], e = rowstart[node + 1];
  const float2* h2 = (const float2*)h;
  float ax = 0.f, ay = 0.f;
  int p = s;
  for (; p + 1 < e; p += 2) {
    int2 pk0 = csr[p];
    int2 pk1 = csr[p + 1];
    float2 hv0 = h2[(size_t)pk0.x * 64 + lane];
    float2 hv1 = h2[(size_t)pk1.x * 64 + lane];
    float w0 = __int_as_float(pk0.y);
    float w1 = __int_as_float(pk1.y);
    ax = fmaf(hv0.x, w0, ax); ay = fmaf(hv0.y, w0, ay);
    ax = fmaf(hv1.x, w1, ax); ay = fmaf(hv1.y, w1, ay);
  }
  if (p < e) {
    int2 pk0 = csr[p];
    float2 hv0 = h2[(size_t)pk0.x * 64 + lane];
    float w0 = __int_as_float(pk0.y);
    ax = fmaf(hv0.x, w0, ax); ay = fmaf(hv0.y, w0, ay);
  }
  float di = dinv[node];
  float sw = di * di;
  float2 hs = h2[(size_t)node * 64 + lane];
  float2 bv = ((const float2*)bias)[lane];
  ax = fmaf(hs.x, sw, ax) + bv.x;
  ay = fmaf(hs.y, sw, ay) + bv.y;
  float2 o;
  o.x = fmaxf(ax, 0.f);
  o.y = fmaxf(ay, 0.f);
  ((float2*)out)[(size_t)node * 64 + lane] = o;
}

// ---------------- LSTM recurrence v4: oct-per-unit, 1024 threads, PINNED weights ----
// 1024 threads = 128 octs. Oct u owns unit u; lane e of oct covers k in [16e,16e+16)
// for ALL 4 gates (16 float4 weights = 64 VGPRs, pinned resident via opaque asm).
// Reduce over 8 lanes: quad_perm xor1 + xor2 (DPP) + xor4 (ds_swizzle).
// h in skewed LDS (group stride 20 floats -> 8 e-lanes hit disjoint bank groups).
// pre is permuted P'[n][u*4+g]; lane e<4 folds pre of gate e into its accumulator.

template <int CTRL>
__device__ __forceinline__ float dppadd(float x) {
  int r = __builtin_amdgcn_update_dpp(0, __float_as_int(x), CTRL, 0xF, 0xF, true);
  return x + __int_as_float(r);
}
__device__ __forceinline__ float swzadd4(float x) {
  int r = __builtin_amdgcn_ds_swizzle(__float_as_int(x), 0x101F);  // xor lane^4
  return x + __int_as_float(r);
}

__device__ __forceinline__ float sigf(float x) {
  return 1.f / (1.f + __expf(-x));
}
__device__ __forceinline__ float tanhf_fast(float x) {
  return 1.f - 2.f / (__expf(2.f * x) + 1.f);
}

typedef float f4v __attribute__((ext_vector_type(4)));

template <bool LAST_ONLY>
__global__ __launch_bounds__(1024, 4) void k_lstm4(const float* __restrict__ pre,
                                                   const float* __restrict__ Whh,
                                                   float* __restrict__ yout) {
  __shared__ float hbuf[2][160];  // 8 groups of 16 floats, stride 20 (skewed)
  const int tid = threadIdx.x;
  const int b = blockIdx.x;
  const int e = tid & 7;   // k-slice selector (16 floats each)
  const int u = tid >> 3;  // hidden unit 0..127

  // weights: Wv[g*4+j] = Whh[g*128+u][16e + 4j .. +3], pinned in VGPRs.
  f4v Wv[16];
#pragma unroll
  for (int g = 0; g < 4; g++)
#pragma unroll
    for (int j = 0; j < 4; j++)
      Wv[g * 4 + j] = *(const f4v*)(Whh + (size_t)(g * 128 + u) * 128 + e * 16 + j * 4);
#pragma unroll
  for (int i = 0; i < 16; i++) {
    // Opaque: forces the 64 weight VGPRs to stay resident across the t-loop
    // (defeats the compiler's in-loop reload/remat of the Whh loads).
    asm volatile("" : "+v"(Wv[i]));
  }

  // init h=0
  if (tid < 160) hbuf[0][tid] = 0.f;
  float cs = 0.f;
  const float* preb = pre + (size_t)b * NT * NG + (u * 4 + (e & 3));
  float pcur = preb[0];
  const int rdoff = e * 20;                       // float offset of my k-group
  const int wroff = (u >> 4) * 20 + (u & 15);     // where h[u] lives
  float* ybase = LAST_ONLY ? (yout + (size_t)b * NH + u)
                           : (yout + (size_t)b * NT * NH + u);
  __syncthreads();

#define LSTM_STEP(CUR, NXT, T)                                                 \
  {                                                                            \
    int tn = (T) + 1; if (tn > NT - 1) tn = NT - 1;                            \
    float pnext = preb[(size_t)tn * NG];                                       \
    const float* hr = &hbuf[CUR][rdoff];                                       \
    f4v h0 = *(const f4v*)(hr);                                                \
    f4v h1 = *(const f4v*)(hr + 4);                                            \
    f4v h2 = *(const f4v*)(hr + 8);                                            \
    f4v h3 = *(const f4v*)(hr + 12);                                           \
    f4v a0 = {0.f, 0.f, 0.f, 0.f}, a1 = a0, a2 = a0, a3 = a0;                  \
    a0 = __builtin_elementwise_fma(Wv[0], h0, a0);                             \
    a1 = __builtin_elementwise_fma(Wv[4], h0, a1);                             \
    a2 = __builtin_elementwise_fma(Wv[8], h0, a2);                             \
    a3 = __builtin_elementwise_fma(Wv[12], h0, a3);                            \
    a0 = __builtin_elementwise_fma(Wv[1], h1, a0);                             \
    a1 = __builtin_elementwise_fma(Wv[5], h1, a1);                             \
    a2 = __builtin_elementwise_fma(Wv[9], h1, a2);                             \
    a3 = __builtin_elementwise_fma(Wv[13], h1, a3);                            \
    a0 = __builtin_elementwise_fma(Wv[2], h2, a0);                             \
    a1 = __builtin_elementwise_fma(Wv[6], h2, a1);                             \
    a2 = __builtin_elementwise_fma(Wv[10], h2, a2);                            \
    a3 = __builtin_elementwise_fma(Wv[14], h2, a3);                            \
    a0 = __builtin_elementwise_fma(Wv[3], h3, a0);                             \
    a1 = __builtin_elementwise_fma(Wv[7], h3, a1);                             \
    a2 = __builtin_elementwise_fma(Wv[11], h3, a2);                            \
    a3 = __builtin_elementwise_fma(Wv[15], h3, a3);                            \
    float s0 = (a0.x + a0.y) + (a0.z + a0.w) + ((e == 0) ? pcur : 0.f);        \
    float s1 = (a1.x + a1.y) + (a1.z + a1.w) + ((e == 1) ? pcur : 0.f);        \
    float s2 = (a2.x + a2.y) + (a2.z + a2.w) + ((e == 2) ? pcur : 0.f);        \
    float s3 = (a3.x + a3.y) + (a3.z + a3.w) + ((e == 3) ? pcur : 0.f);        \
    s0 = dppadd<0xB1>(s0); s0 = dppadd<0x4E>(s0); s0 = swzadd4(s0);            \
    s1 = dppadd<0xB1>(s1); s1 = dppadd<0x4E>(s1); s1 = swzadd4(s1);            \
    s2 = dppadd<0xB1>(s2); s2 = dppadd<0x4E>(s2); s2 = swzadd4(s2);            \
    s3 = dppadd<0xB1>(s3); s3 = dppadd<0x4E>(s3); s3 = swzadd4(s3);            \
    float si = sigf(s0), sf = sigf(s1), tg = tanhf_fast(s2), so = sigf(s3);    \
    cs = sf * cs + si * tg;                                                    \
    float hnew = so * tanhf_fast(cs);                                          \
    if (e == 0) hbuf[NXT][wroff] = hnew;                                       \
    if (!LAST_ONLY) {                                                          \
      if (e == 1) ybase[(size_t)(T) * NH] = hnew;                              \
    } else if ((T) == NT - 1) {                                                \
      if (e == 1) *ybase = hnew;                                               \
    }                                                                          \
    pcur = pnext;                                                              \
    __syncthreads();                                                           \
  }

  for (int t = 0; t < NT; t += 2) {
    LSTM_STEP(0, 1, t);
    LSTM_STEP(1, 0, t + 1);
  }
#undef LSTM_STEP
}

// ---------------- host ----------------

extern "C" void kernel_launch(void* const* d_in, const int* in_sizes, int n_in,
                              void* d_out, int out_size, void* d_ws, size_t ws_size,
                              hipStream_t stream) {
  const float* x    = (const float*)d_in[0];   // [64,256,64] -> [16384,64]
  const float* dist = (const float*)d_in[1];   // [64,64]
  const int*   ei   = (const int*)d_in[2];     // [2, 524288]
  const float* W0   = (const float*)d_in[3];   // [4160,128]
  const float* b0   = (const float*)d_in[4];
  const float* W1   = (const float*)d_in[5];   // [128,128]
  const float* b1   = (const float*)d_in[6];
  const float* W2   = (const float*)d_in[7];
  const float* b2   = (const float*)d_in[8];
  const float* Wih0 = (const float*)d_in[9];   // [512,128]
  const float* Whh0 = (const float*)d_in[10];  // [512,128]
  const float* bih0 = (const float*)d_in[11];
  const float* bhh0 = (const float*)d_in[12];
  const float* Wih1 = (const float*)d_in[13];
  const float* Whh1 = (const float*)d_in[14];
  const float* bih1 = (const float*)d_in[15];
  const float* bhh1 = (const float*)d_in[16];
  const float* fcW  = (const float*)d_in[17];  // [768,128]
  const float* fcb  = (const float*)d_in[18];
  float* out = (float*)d_out;

  char* ws = (char*)d_ws;
  size_t off = 0;
  auto alloc = [&](size_t bytes) -> void* {
    void* p = ws + off;
    off += (bytes + 255) & ~(size_t)255;
    return p;
  };
  float* bufA     = (float*)alloc((size_t)NN * 128 * 4);
  float* bufB     = (float*)alloc((size_t)NN * 128 * 4);
  float* pre      = (float*)alloc((size_t)NN * 512 * 4);
  int2*  csr      = (int2*)alloc((size_t)NE * 8);
  int*   counts   = (int*)alloc((size_t)NN * 4);
  int*   fillc    = (int*)alloc((size_t)NN * 4);
  int*   rowstart = (int*)alloc((size_t)(NN + 1) * 4);
  float* dinv     = (float*)alloc((size_t)NN * 4);
  float* dvec     = (float*)alloc(128 * 4);
  float* hlast    = (float*)alloc(64 * 128 * 4);
  float* wt0      = (float*)alloc(128 * 64 * 4);
  float* wt1      = (float*)alloc(128 * 128 * 4);
  float* wt2      = (float*)alloc(128 * 128 * 4);
  (void)ws_size; (void)in_sizes; (void)n_in; (void)out_size;

  const int* srcIdx = ei;
  const int* dstIdx = ei + NE;

  hipMemsetAsync(counts, 0, (size_t)NN * 4, stream);
  hipMemsetAsync(fillc, 0, (size_t)NN * 4, stream);

  // weight transposes + distance vector
  k_transpose<<<(64 * 128 + 255) / 256, 256, 0, stream>>>(W0, wt0, 64, 128);
  k_transpose<<<(128 * 128 + 255) / 256, 256, 0, stream>>>(W1, wt1, 128, 128);
  k_transpose<<<(128 * 128 + 255) / 256, 256, 0, stream>>>(W2, wt2, 128, 128);
  k_dvec<<<128, 256, 0, stream>>>(dist, W0, dvec);

  // CSR build (reused by all 3 GCN layers)
  k_count<<<NE / 256, 256, 0, stream>>>(dstIdx, counts);
  k_scan<<<1, 1024, 0, stream>>>(counts, rowstart);
  k_dinv<<<NN / 256, 256, 0, stream>>>(counts, dinv);
  k_fill<<<NE / 256, 256, 0, stream>>>(srcIdx, dstIdx, rowstart, fillc, dinv, csr);

  // GCN layer 0: h0 = x @ W0a^T + dvec  (bias/relu happen after aggregation)
  dim3 gH(NN / 64, 128 / 64);
  k_gemm_abt<64, false><<<gH, 256, 0, stream>>>(x, wt0, dvec, nullptr, bufB, 128);
  k_agg<<<NN / 4, 256, 0, stream>>>(bufB, rowstart, csr, dinv, b0, bufA);
  // GCN layer 1
  k_gemm_abt<128, false><<<gH, 256, 0, stream>>>(bufA, wt1, nullptr, nullptr, bufB, 128);
  k_agg<<<NN / 4, 256, 0, stream>>>(bufB, rowstart, csr, dinv, b1, bufA);
  // GCN layer 2
  k_gemm_abt<128, false><<<gH, 256, 0, stream>>>(bufA, wt2, nullptr, nullptr, bufB, 128);
  k_agg<<<NN / 4, 256, 0, stream>>>(bufB, rowstart, csr, dinv, b2, bufA);

  // LSTM layer 0: pre (permuted) = feat @ Wih0^T + bih0 + bhh0 ; recurrence -> y1 (bufB)
  dim3 gP(NN / 64, 512 / 64);
  k_gemm_abt<128, false, true><<<gP, 256, 0, stream>>>(bufA, Wih0, bih0, bhh0, pre, 512);
  k_lstm4<false><<<64, 1024, 0, stream>>>(pre, Whh0, bufB);
  // LSTM layer 1
  k_gemm_abt<128, false, true><<<gP, 256, 0, stream>>>(bufB, Wih1, bih1, bhh1, pre, 512);
  k_lstm4<true><<<64, 1024, 0, stream>>>(pre, Whh1, hlast);

  // FC: out[64,768] = hlast @ fcW^T + fcb
  dim3 gF(1, NOUT / 64);
  k_gemm_abt<128, false><<<gF, 256, 0, stream>>>(hlast, fcW, fcb, nullptr, out, NOUT);
}

// Round 5
// 951.894 us; speedup vs baseline: 1.1625x; 1.1601x over previous
//
#include <hip/hip_runtime.h>
#include <hip/hip_bf16.h>
#include <cstdint>
#include <cstddef>

// Problem constants
#define NB 64      // batch
#define NT 256     // time steps
#define NL 64      // links
#define NH 128     // hidden
#define NN 16384   // nodes = NB*NT
#define NE 524288  // edges
#define NG 512     // 4*NH gates
#define NOUT 768   // 12*NL

// ---------------- small prep kernels ----------------

// Wt[n][k] = W[k][n], W is [K, Nout] row-major
__global__ __launch_bounds__(256) void k_transpose(const float* __restrict__ W,
                                                   float* __restrict__ Wt,
                                                   int K, int Nout) {
  int i = blockIdx.x * 256 + threadIdx.x;
  if (i < K * Nout) {
    int k = i / Nout, n = i % Nout;
    Wt[n * K + k] = W[i];
  }
}

// dvec[j] = sum_m dist[m] * W0[(64+m)*128 + j]   (128 blocks, one per j)
__global__ __launch_bounds__(256) void k_dvec(const float* __restrict__ dist,
                                              const float* __restrict__ W0,
                                              float* __restrict__ dvec) {
  __shared__ float red[256];
  int j = blockIdx.x;
  int t = threadIdx.x;
  float acc = 0.f;
  for (int m = t; m < 4096; m += 256)
    acc += dist[m] * W0[(size_t)(64 + m) * 128 + j];
  red[t] = acc;
  __syncthreads();
  for (int off = 128; off > 0; off >>= 1) {
    if (t < off) red[t] += red[t + off];
    __syncthreads();
  }
  if (t == 0) dvec[j] = red[0];
}

__global__ __launch_bounds__(256) void k_count(const int* __restrict__ dst,
                                               int* __restrict__ counts) {
  int i = blockIdx.x * 256 + threadIdx.x;
  atomicAdd(&counts[dst[i]], 1);
}

__global__ __launch_bounds__(256) void k_dinv(const int* __restrict__ counts,
                                              float* __restrict__ dinv) {
  int n = blockIdx.x * 256 + threadIdx.x;
  dinv[n] = rsqrtf((float)counts[n] + 1.0f);
}

// exclusive scan of counts[16384] -> rowstart[16385]; single block of 1024
__global__ __launch_bounds__(1024) void k_scan(const int* __restrict__ counts,
                                               int* __restrict__ rowstart) {
  __shared__ int part[1024];
  int t = threadIdx.x;
  int base = t * 16;
  int local[16];
  int s = 0;
#pragma unroll
  for (int i = 0; i < 16; i++) { local[i] = s; s += counts[base + i]; }
  part[t] = s;
  __syncthreads();
  for (int off = 1; off < 1024; off <<= 1) {
    int v = (t >= off) ? part[t - off] : 0;
    __syncthreads();
    part[t] += v;
    __syncthreads();
  }
  int prefix = (t == 0) ? 0 : part[t - 1];
#pragma unroll
  for (int i = 0; i < 16; i++) rowstart[base + i] = prefix + local[i];
  if (t == 1023) rowstart[16384] = part[1023];
}

__global__ __launch_bounds__(256) void k_fill(const int* __restrict__ src,
                                              const int* __restrict__ dst,
                                              const int* __restrict__ rowstart,
                                              int* __restrict__ fill,
                                              const float* __restrict__ dinv,
                                              int2* __restrict__ csr) {
  int e = blockIdx.x * 256 + threadIdx.x;
  int sN = src[e], dN = dst[e];
  int pos = rowstart[dN] + atomicAdd(&fill[dN], 1);
  csr[pos] = make_int2(sN, __float_as_int(dinv[sN] * dinv[dN]));
}

// ---------------- GEMM: C[M,Nn] = A[M,K] * B[Nn,K]^T (+bias0+bias1) ----------------
// grid (M/64, Nn/64), block 256. K = 64 or 128.
// PERMC: store col' = (col&127)*4 + (col>>7)  (gate-interleaved layout for LSTM pre)
template <int K, bool RELU, bool PERMC = false>
__global__ __launch_bounds__(256) void k_gemm_abt(const float* __restrict__ A,
                                                  const float* __restrict__ Bm,
                                                  const float* __restrict__ bias0,
                                                  const float* __restrict__ bias1,
                                                  float* __restrict__ C, int Nn) {
  __shared__ float As[64][K + 1];
  __shared__ float Bs[64][K + 1];
  const int tid = threadIdx.x;
  const int bm = blockIdx.x, bn = blockIdx.y;
  const int VPR = K / 4;  // float4 per row
  for (int i = tid; i < 64 * VPR; i += 256) {
    int r = i / VPR, v = (i % VPR) * 4;
    float4 q = *(const float4*)(A + (size_t)(bm * 64 + r) * K + v);
    As[r][v] = q.x; As[r][v + 1] = q.y; As[r][v + 2] = q.z; As[r][v + 3] = q.w;
  }
  for (int i = tid; i < 64 * VPR; i += 256) {
    int r = i / VPR, v = (i % VPR) * 4;
    float4 q = *(const float4*)(Bm + (size_t)(bn * 64 + r) * K + v);
    Bs[r][v] = q.x; Bs[r][v + 1] = q.y; Bs[r][v + 2] = q.z; Bs[r][v + 3] = q.w;
  }
  __syncthreads();
  const int tr = (tid >> 4) << 2;   // output rows tr..tr+3
  const int tc = (tid & 15) << 2;   // output cols tc..tc+3
  float acc[4][4] = {};
#pragma unroll 4
  for (int k = 0; k < K; k++) {
    float a0 = As[tr + 0][k], a1 = As[tr + 1][k], a2 = As[tr + 2][k], a3 = As[tr + 3][k];
    float b0 = Bs[tc + 0][k], b1 = Bs[tc + 1][k], b2 = Bs[tc + 2][k], b3 = Bs[tc + 3][k];
    acc[0][0] += a0 * b0; acc[0][1] += a0 * b1; acc[0][2] += a0 * b2; acc[0][3] += a0 * b3;
    acc[1][0] += a1 * b0; acc[1][1] += a1 * b1; acc[1][2] += a1 * b2; acc[1][3] += a1 * b3;
    acc[2][0] += a2 * b0; acc[2][1] += a2 * b1; acc[2][2] += a2 * b2; acc[2][3] += a2 * b3;
    acc[3][0] += a3 * b0; acc[3][1] += a3 * b1; acc[3][2] += a3 * b2; acc[3][3] += a3 * b3;
  }
#pragma unroll
  for (int i2 = 0; i2 < 4; i2++) {
    int row = bm * 64 + tr + i2;
#pragma unroll
    for (int j2 = 0; j2 < 4; j2++) {
      int col = bn * 64 + tc + j2;
      float v = acc[i2][j2];
      if (bias0) v += bias0[col];
      if (bias1) v += bias1[col];
      if (RELU) v = fmaxf(v, 0.f);
      int colw = PERMC ? ((col & 127) * 4 + (col >> 7)) : col;
      C[(size_t)row * Nn + colw] = v;
    }
  }
}

// ---------------- GCN aggregation (float2 lanes, packed CSR) ----------------
__global__ __launch_bounds__(256) void k_agg(const float* __restrict__ h,
                                             const int* __restrict__ rowstart,
                                             const int2* __restrict__ csr,
                                             const float* __restrict__ dinv,
                                             const float* __restrict__ bias,
                                             float* __restrict__ out) {
  int node = blockIdx.x * 4 + (threadIdx.x >> 6);
  int lane = threadIdx.x & 63;
  int s = rowstart[node], e = rowstart[node + 1];
  const float2* h2 = (const float2*)h;
  float ax = 0.f, ay = 0.f;
  int p = s;
  for (; p + 1 < e; p += 2) {
    int2 pk0 = csr[p];
    int2 pk1 = csr[p + 1];
    float2 hv0 = h2[(size_t)pk0.x * 64 + lane];
    float2 hv1 = h2[(size_t)pk1.x * 64 + lane];
    float w0 = __int_as_float(pk0.y);
    float w1 = __int_as_float(pk1.y);
    ax = fmaf(hv0.x, w0, ax); ay = fmaf(hv0.y, w0, ay);
    ax = fmaf(hv1.x, w1, ax); ay = fmaf(hv1.y, w1, ay);
  }
  if (p < e) {
    int2 pk0 = csr[p];
    float2 hv0 = h2[(size_t)pk0.x * 64 + lane];
    float w0 = __int_as_float(pk0.y);
    ax = fmaf(hv0.x, w0, ax); ay = fmaf(hv0.y, w0, ay);
  }
  float di = dinv[node];
  float sw = di * di;
  float2 hs = h2[(size_t)node * 64 + lane];
  float2 bv = ((const float2*)bias)[lane];
  ax = fmaf(hs.x, sw, ax) + bv.x;
  ay = fmaf(hs.y, sw, ay) + bv.y;
  float2 o;
  o.x = fmaxf(ax, 0.f);
  o.y = fmaxf(ay, 0.f);
  ((float2*)out)[(size_t)node * 64 + lane] = o;
}

// ---------------- LSTM recurrence v5: quad-per-unit, IN-LOOP pinned weights ----------
// 512 threads = 128 quads. Quad u owns unit u (all 4 gates); lane c4 covers
// k in [32*c4, 32*c4+32). Weights: 64 float2 = 128 VGPRs, forced loop-resident by a
// read-write asm pin INSIDE the t-loop (an asm "may modify" its "+v" operands, so the
// compiler cannot rematerialize the Whh loads; launch_bounds(512,2) grants 256 VGPRs
// so there is no pressure to spill). FMAs on float2 -> v_pk_fma_f32.
// Reduce over the 4 quad lanes: pure-DPP quad_perm xor1 + xor2 (no lgkm traffic).
// pre is permuted P'[n][u*4+g]; lane c4 folds pre of gate c4 in before the reduce.

template <int CTRL>
__device__ __forceinline__ float dppadd(float x) {
  int r = __builtin_amdgcn_update_dpp(0, __float_as_int(x), CTRL, 0xF, 0xF, true);
  return x + __int_as_float(r);
}
// quad_perm[1,0,3,2] = 0xB1 (xor1), quad_perm[2,3,0,1] = 0x4E (xor2)

__device__ __forceinline__ float sigf(float x) {
  return 1.f / (1.f + __expf(-x));
}
__device__ __forceinline__ float tanhf_fast(float x) {
  return 1.f - 2.f / (__expf(2.f * x) + 1.f);
}

typedef float f2v __attribute__((ext_vector_type(2)));
typedef float f4v __attribute__((ext_vector_type(4)));

template <bool LAST_ONLY>
__global__ __launch_bounds__(512, 2) void k_lstm5(const float* __restrict__ pre,
                                                  const float* __restrict__ Whh,
                                                  float* __restrict__ yout) {
  __shared__ float hbuf[2][128];
  const int tid = threadIdx.x;
  const int b = blockIdx.x;
  const int c4 = tid & 3;   // k-quarter
  const int u = tid >> 2;   // hidden unit 0..127

  // rotated float4 indices into h (R2-verified conflict-free pattern)
  int hidx[8];
#pragma unroll
  for (int j = 0; j < 8; j++) hidx[j] = c4 * 8 + (((u & 7) + 2 * c4 + j) & 7);

  // weights: W[g][j][p] = Whh[g*128+u][4*hidx[j] + 2p .. +1]  (64 float2 = 128 VGPR)
  f2v W[4][8][2];
#pragma unroll
  for (int g = 0; g < 4; g++)
#pragma unroll
    for (int j = 0; j < 8; j++) {
      const float* p = Whh + (size_t)(g * 128 + u) * 128 + hidx[j] * 4;
      W[g][j][0] = *(const f2v*)(p);
      W[g][j][1] = *(const f2v*)(p + 2);
    }

  if (tid < 128) hbuf[0][tid] = 0.f;
  float cs = 0.f;
  const float* preb = pre + (size_t)b * NT * NG + tid;  // tid == u*4 + c4 == P' column
  float pcur = preb[0];
  float* ybase = LAST_ONLY ? (yout + (size_t)b * NH + u)
                           : (yout + (size_t)b * NT * NH + u);
  __syncthreads();

#define LSTM_STEP(CUR, NXT, T)                                                 \
  {                                                                            \
    int tn = (T) + 1; if (tn > NT - 1) tn = NT - 1;                            \
    float pnext = preb[(size_t)tn * NG];                                       \
    const f4v* hp = (const f4v*)&hbuf[CUR][0];                                 \
    f2v a0 = {0.f, 0.f}, a1 = a0, a2 = a0, a3 = a0;                            \
    _Pragma("unroll")                                                          \
    for (int j = 0; j < 8; j++) {                                              \
      f4v hv = hp[hidx[j]];                                                    \
      f2v hlo = __builtin_shufflevector(hv, hv, 0, 1);                         \
      f2v hhi = __builtin_shufflevector(hv, hv, 2, 3);                         \
      a0 = __builtin_elementwise_fma(W[0][j][0], hlo, a0);                     \
      a0 = __builtin_elementwise_fma(W[0][j][1], hhi, a0);                     \
      a1 = __builtin_elementwise_fma(W[1][j][0], hlo, a1);                     \
      a1 = __builtin_elementwise_fma(W[1][j][1], hhi, a1);                     \
      a2 = __builtin_elementwise_fma(W[2][j][0], hlo, a2);                     \
      a2 = __builtin_elementwise_fma(W[2][j][1], hhi, a2);                     \
      a3 = __builtin_elementwise_fma(W[3][j][0], hlo, a3);                     \
      a3 = __builtin_elementwise_fma(W[3][j][1], hhi, a3);                     \
    }                                                                          \
    float s0 = (a0.x + a0.y) + ((c4 == 0) ? pcur : 0.f);                       \
    float s1 = (a1.x + a1.y) + ((c4 == 1) ? pcur : 0.f);                       \
    float s2 = (a2.x + a2.y) + ((c4 == 2) ? pcur : 0.f);                       \
    float s3 = (a3.x + a3.y) + ((c4 == 3) ? pcur : 0.f);                       \
    s0 = dppadd<0xB1>(s0); s0 = dppadd<0x4E>(s0);                              \
    s1 = dppadd<0xB1>(s1); s1 = dppadd<0x4E>(s1);                              \
    s2 = dppadd<0xB1>(s2); s2 = dppadd<0x4E>(s2);                              \
    s3 = dppadd<0xB1>(s3); s3 = dppadd<0x4E>(s3);                              \
    float si = sigf(s0), sf = sigf(s1), tg = tanhf_fast(s2), so = sigf(s3);    \
    cs = sf * cs + si * tg;                                                    \
    float hnew = so * tanhf_fast(cs);                                          \
    if (c4 == 0) hbuf[NXT][u] = hnew;                                          \
    if (!LAST_ONLY) {                                                          \
      if (c4 == 1) ybase[(size_t)(T) * NH] = hnew;                             \
    } else if ((T) == NT - 1) {                                                \
      if (c4 == 1) *ybase = hnew;                                              \
    }                                                                          \
    pcur = pnext;                                                              \
    __syncthreads();                                                           \
  }

  for (int t = 0; t < NT; t += 2) {
    // IN-LOOP pin: weights must be live-in to every iteration in VGPRs; the asm
    // "may modify" them, so reload-from-global afterwards would be incorrect ->
    // the allocator has to keep all 128 weight VGPRs resident across the loop.
#pragma unroll
    for (int g = 0; g < 4; g++)
#pragma unroll
      for (int j = 0; j < 8; j++)
        asm volatile("" : "+v"(W[g][j][0]), "+v"(W[g][j][1]));
    LSTM_STEP(0, 1, t);
    LSTM_STEP(1, 0, t + 1);
  }
#undef LSTM_STEP
}

// ---------------- host ----------------

extern "C" void kernel_launch(void* const* d_in, const int* in_sizes, int n_in,
                              void* d_out, int out_size, void* d_ws, size_t ws_size,
                              hipStream_t stream) {
  const float* x    = (const float*)d_in[0];   // [64,256,64] -> [16384,64]
  const float* dist = (const float*)d_in[1];   // [64,64]
  const int*   ei   = (const int*)d_in[2];     // [2, 524288]
  const float* W0   = (const float*)d_in[3];   // [4160,128]
  const float* b0   = (const float*)d_in[4];
  const float* W1   = (const float*)d_in[5];   // [128,128]
  const float* b1   = (const float*)d_in[6];
  const float* W2   = (const float*)d_in[7];
  const float* b2   = (const float*)d_in[8];
  const float* Wih0 = (const float*)d_in[9];   // [512,128]
  const float* Whh0 = (const float*)d_in[10];  // [512,128]
  const float* bih0 = (const float*)d_in[11];
  const float* bhh0 = (const float*)d_in[12];
  const float* Wih1 = (const float*)d_in[13];
  const float* Whh1 = (const float*)d_in[14];
  const float* bih1 = (const float*)d_in[15];
  const float* bhh1 = (const float*)d_in[16];
  const float* fcW  = (const float*)d_in[17];  // [768,128]
  const float* fcb  = (const float*)d_in[18];
  float* out = (float*)d_out;

  char* ws = (char*)d_ws;
  size_t off = 0;
  auto alloc = [&](size_t bytes) -> void* {
    void* p = ws + off;
    off += (bytes + 255) & ~(size_t)255;
    return p;
  };
  float* bufA     = (float*)alloc((size_t)NN * 128 * 4);
  float* bufB     = (float*)alloc((size_t)NN * 128 * 4);
  float* pre      = (float*)alloc((size_t)NN * 512 * 4);
  int2*  csr      = (int2*)alloc((size_t)NE * 8);
  int*   counts   = (int*)alloc((size_t)NN * 4);
  int*   fillc    = (int*)alloc((size_t)NN * 4);
  int*   rowstart = (int*)alloc((size_t)(NN + 1) * 4);
  float* dinv     = (float*)alloc((size_t)NN * 4);
  float* dvec     = (float*)alloc(128 * 4);
  float* hlast    = (float*)alloc(64 * 128 * 4);
  float* wt0      = (float*)alloc(128 * 64 * 4);
  float* wt1      = (float*)alloc(128 * 128 * 4);
  float* wt2      = (float*)alloc(128 * 128 * 4);
  (void)ws_size; (void)in_sizes; (void)n_in; (void)out_size;

  const int* srcIdx = ei;
  const int* dstIdx = ei + NE;

  hipMemsetAsync(counts, 0, (size_t)NN * 4, stream);
  hipMemsetAsync(fillc, 0, (size_t)NN * 4, stream);

  // weight transposes + distance vector
  k_transpose<<<(64 * 128 + 255) / 256, 256, 0, stream>>>(W0, wt0, 64, 128);
  k_transpose<<<(128 * 128 + 255) / 256, 256, 0, stream>>>(W1, wt1, 128, 128);
  k_transpose<<<(128 * 128 + 255) / 256, 256, 0, stream>>>(W2, wt2, 128, 128);
  k_dvec<<<128, 256, 0, stream>>>(dist, W0, dvec);

  // CSR build (reused by all 3 GCN layers)
  k_count<<<NE / 256, 256, 0, stream>>>(dstIdx, counts);
  k_scan<<<1, 1024, 0, stream>>>(counts, rowstart);
  k_dinv<<<NN / 256, 256, 0, stream>>>(counts, dinv);
  k_fill<<<NE / 256, 256, 0, stream>>>(srcIdx, dstIdx, rowstart, fillc, dinv, csr);

  // GCN layer 0: h0 = x @ W0a^T + dvec  (bias/relu happen after aggregation)
  dim3 gH(NN / 64, 128 / 64);
  k_gemm_abt<64, false><<<gH, 256, 0, stream>>>(x, wt0, dvec, nullptr, bufB, 128);
  k_agg<<<NN / 4, 256, 0, stream>>>(bufB, rowstart, csr, dinv, b0, bufA);
  // GCN layer 1
  k_gemm_abt<128, false><<<gH, 256, 0, stream>>>(bufA, wt1, nullptr, nullptr, bufB, 128);
  k_agg<<<NN / 4, 256, 0, stream>>>(bufB, rowstart, csr, dinv, b1, bufA);
  // GCN layer 2
  k_gemm_abt<128, false><<<gH, 256, 0, stream>>>(bufA, wt2, nullptr, nullptr, bufB, 128);
  k_agg<<<NN / 4, 256, 0, stream>>>(bufB, rowstart, csr, dinv, b2, bufA);

  // LSTM layer 0: pre (permuted) = feat @ Wih0^T + bih0 + bhh0 ; recurrence -> y1 (bufB)
  dim3 gP(NN / 64, 512 / 64);
  k_gemm_abt<128, false, true><<<gP, 256, 0, stream>>>(bufA, Wih0, bih0, bhh0, pre, 512);
  k_lstm5<false><<<64, 512, 0, stream>>>(pre, Whh0, bufB);
  // LSTM layer 1
  k_gemm_abt<128, false, true><<<gP, 256, 0, stream>>>(bufB, Wih1, bih1, bhh1, pre, 512);
  k_lstm5<true><<<64, 512, 0, stream>>>(pre, Whh1, hlast);

  // FC: out[64,768] = hlast @ fcW^T + fcb
  dim3 gF(1, NOUT / 64);
  k_gemm_abt<128, false><<<gF, 256, 0, stream>>>(hlast, fcW, fcb, nullptr, out, NOUT);
}

// Round 6
// 919.777 us; speedup vs baseline: 1.2031x; 1.0349x over previous
//
#include <hip/hip_runtime.h>
#include <hip/hip_bf16.h>
#include <cstdint>
#include <cstddef>

// Problem constants
#define NB 64      // batch
#define NT 256     // time steps
#define NL 64      // links
#define NH 128     // hidden
#define NN 16384   // nodes = NB*NT
#define NE 524288  // edges
#define NG 512     // 4*NH gates
#define NOUT 768   // 12*NL

// ---------------- small prep kernels ----------------

// Wt[n][k] = W[k][n], W is [K, Nout] row-major
__global__ __launch_bounds__(256) void k_transpose(const float* __restrict__ W,
                                                   float* __restrict__ Wt,
                                                   int K, int Nout) {
  int i = blockIdx.x * 256 + threadIdx.x;
  if (i < K * Nout) {
    int k = i / Nout, n = i % Nout;
    Wt[n * K + k] = W[i];
  }
}

// dvec[j] = sum_m dist[m] * W0[(64+m)*128 + j]   (128 blocks, one per j)
__global__ __launch_bounds__(256) void k_dvec(const float* __restrict__ dist,
                                              const float* __restrict__ W0,
                                              float* __restrict__ dvec) {
  __shared__ float red[256];
  int j = blockIdx.x;
  int t = threadIdx.x;
  float acc = 0.f;
  for (int m = t; m < 4096; m += 256)
    acc += dist[m] * W0[(size_t)(64 + m) * 128 + j];
  red[t] = acc;
  __syncthreads();
  for (int off = 128; off > 0; off >>= 1) {
    if (t < off) red[t] += red[t + off];
    __syncthreads();
  }
  if (t == 0) dvec[j] = red[0];
}

__global__ __launch_bounds__(256) void k_count(const int* __restrict__ dst,
                                               int* __restrict__ counts) {
  int i = blockIdx.x * 256 + threadIdx.x;
  atomicAdd(&counts[dst[i]], 1);
}

__global__ __launch_bounds__(256) void k_dinv(const int* __restrict__ counts,
                                              float* __restrict__ dinv) {
  int n = blockIdx.x * 256 + threadIdx.x;
  dinv[n] = rsqrtf((float)counts[n] + 1.0f);
}

// exclusive scan of counts[16384] -> rowstart[16385]; single block of 1024
__global__ __launch_bounds__(1024) void k_scan(const int* __restrict__ counts,
                                               int* __restrict__ rowstart) {
  __shared__ int part[1024];
  int t = threadIdx.x;
  int base = t * 16;
  int local[16];
  int s = 0;
#pragma unroll
  for (int i = 0; i < 16; i++) { local[i] = s; s += counts[base + i]; }
  part[t] = s;
  __syncthreads();
  for (int off = 1; off < 1024; off <<= 1) {
    int v = (t >= off) ? part[t - off] : 0;
    __syncthreads();
    part[t] += v;
    __syncthreads();
  }
  int prefix = (t == 0) ? 0 : part[t - 1];
#pragma unroll
  for (int i = 0; i < 16; i++) rowstart[base + i] = prefix + local[i];
  if (t == 1023) rowstart[16384] = part[1023];
}

__global__ __launch_bounds__(256) void k_fill(const int* __restrict__ src,
                                              const int* __restrict__ dst,
                                              const int* __restrict__ rowstart,
                                              int* __restrict__ fill,
                                              const float* __restrict__ dinv,
                                              int2* __restrict__ csr) {
  int e = blockIdx.x * 256 + threadIdx.x;
  int sN = src[e], dN = dst[e];
  int pos = rowstart[dN] + atomicAdd(&fill[dN], 1);
  csr[pos] = make_int2(sN, __float_as_int(dinv[sN] * dinv[dN]));
}

// ---------------- GEMM: C[M,Nn] = A[M,K] * B[Nn,K]^T (+bias0+bias1) ----------------
// grid (M/64, Nn/64), block 256. K = 64 or 128.
// PERMC: store col' = (col&127)*4 + (col>>7)  (gate-interleaved layout for LSTM pre)
template <int K, bool RELU, bool PERMC = false>
__global__ __launch_bounds__(256) void k_gemm_abt(const float* __restrict__ A,
                                                  const float* __restrict__ Bm,
                                                  const float* __restrict__ bias0,
                                                  const float* __restrict__ bias1,
                                                  float* __restrict__ C, int Nn) {
  __shared__ float As[64][K + 1];
  __shared__ float Bs[64][K + 1];
  const int tid = threadIdx.x;
  const int bm = blockIdx.x, bn = blockIdx.y;
  const int VPR = K / 4;  // float4 per row
  for (int i = tid; i < 64 * VPR; i += 256) {
    int r = i / VPR, v = (i % VPR) * 4;
    float4 q = *(const float4*)(A + (size_t)(bm * 64 + r) * K + v);
    As[r][v] = q.x; As[r][v + 1] = q.y; As[r][v + 2] = q.z; As[r][v + 3] = q.w;
  }
  for (int i = tid; i < 64 * VPR; i += 256) {
    int r = i / VPR, v = (i % VPR) * 4;
    float4 q = *(const float4*)(Bm + (size_t)(bn * 64 + r) * K + v);
    Bs[r][v] = q.x; Bs[r][v + 1] = q.y; Bs[r][v + 2] = q.z; Bs[r][v + 3] = q.w;
  }
  __syncthreads();
  const int tr = (tid >> 4) << 2;   // output rows tr..tr+3
  const int tc = (tid & 15) << 2;   // output cols tc..tc+3
  float acc[4][4] = {};
#pragma unroll 4
  for (int k = 0; k < K; k++) {
    float a0 = As[tr + 0][k], a1 = As[tr + 1][k], a2 = As[tr + 2][k], a3 = As[tr + 3][k];
    float b0 = Bs[tc + 0][k], b1 = Bs[tc + 1][k], b2 = Bs[tc + 2][k], b3 = Bs[tc + 3][k];
    acc[0][0] += a0 * b0; acc[0][1] += a0 * b1; acc[0][2] += a0 * b2; acc[0][3] += a0 * b3;
    acc[1][0] += a1 * b0; acc[1][1] += a1 * b1; acc[1][2] += a1 * b2; acc[1][3] += a1 * b3;
    acc[2][0] += a2 * b0; acc[2][1] += a2 * b1; acc[2][2] += a2 * b2; acc[2][3] += a2 * b3;
    acc[3][0] += a3 * b0; acc[3][1] += a3 * b1; acc[3][2] += a3 * b2; acc[3][3] += a3 * b3;
  }
#pragma unroll
  for (int i2 = 0; i2 < 4; i2++) {
    int row = bm * 64 + tr + i2;
#pragma unroll
    for (int j2 = 0; j2 < 4; j2++) {
      int col = bn * 64 + tc + j2;
      float v = acc[i2][j2];
      if (bias0) v += bias0[col];
      if (bias1) v += bias1[col];
      if (RELU) v = fmaxf(v, 0.f);
      int colw = PERMC ? ((col & 127) * 4 + (col >> 7)) : col;
      C[(size_t)row * Nn + colw] = v;
    }
  }
}

// ---------------- GCN aggregation (float2 lanes, packed CSR) ----------------
__global__ __launch_bounds__(256) void k_agg(const float* __restrict__ h,
                                             const int* __restrict__ rowstart,
                                             const int2* __restrict__ csr,
                                             const float* __restrict__ dinv,
                                             const float* __restrict__ bias,
                                             float* __restrict__ out) {
  int node = blockIdx.x * 4 + (threadIdx.x >> 6);
  int lane = threadIdx.x & 63;
  int s = rowstart[node], e = rowstart[node + 1];
  const float2* h2 = (const float2*)h;
  float ax = 0.f, ay = 0.f;
  int p = s;
  for (; p + 1 < e; p += 2) {
    int2 pk0 = csr[p];
    int2 pk1 = csr[p + 1];
    float2 hv0 = h2[(size_t)pk0.x * 64 + lane];
    float2 hv1 = h2[(size_t)pk1.x * 64 + lane];
    float w0 = __int_as_float(pk0.y);
    float w1 = __int_as_float(pk1.y);
    ax = fmaf(hv0.x, w0, ax); ay = fmaf(hv0.y, w0, ay);
    ax = fmaf(hv1.x, w1, ax); ay = fmaf(hv1.y, w1, ay);
  }
  if (p < e) {
    int2 pk0 = csr[p];
    float2 hv0 = h2[(size_t)pk0.x * 64 + lane];
    float w0 = __int_as_float(pk0.y);
    ax = fmaf(hv0.x, w0, ax); ay = fmaf(hv0.y, w0, ay);
  }
  float di = dinv[node];
  float sw = di * di;
  float2 hs = h2[(size_t)node * 64 + lane];
  float2 bv = ((const float2*)bias)[lane];
  ax = fmaf(hs.x, sw, ax) + bv.x;
  ay = fmaf(hs.y, sw, ay) + bv.y;
  float2 o;
  o.x = fmaxf(ax, 0.f);
  o.y = fmaxf(ay, 0.f);
  ((float2*)out)[(size_t)node * 64 + lane] = o;
}

// ---------------- LSTM recurrence v6: quad-per-unit, NAMED weight registers ----------
// 512 threads = 128 quads. Quad u owns unit u (all 4 gates); lane c4 covers
// k in [32*c4, 32*c4+32). The 32 weight float4s are 32 INDIVIDUALLY NAMED SSA values
// (no array -> no alloca -> nothing for the allocator to back with scratch), each
// pinned loop-resident by an in-loop read-write asm. 128 weight VGPRs + ~50 temps
// fits the 256-VGPR budget of __launch_bounds__(512,2).
// Reduce over the 4 quad lanes: pure-DPP quad_perm xor1 + xor2.
// pre is permuted P'[n][u*4+g]; lane c4 folds pre of gate c4 in before the reduce.

template <int CTRL>
__device__ __forceinline__ float dppadd(float x) {
  int r = __builtin_amdgcn_update_dpp(0, __float_as_int(x), CTRL, 0xF, 0xF, true);
  return x + __int_as_float(r);
}
// quad_perm[1,0,3,2] = 0xB1 (xor1), quad_perm[2,3,0,1] = 0x4E (xor2)

__device__ __forceinline__ float sigf(float x) {
  return 1.f / (1.f + __expf(-x));
}
__device__ __forceinline__ float tanhf_fast(float x) {
  return 1.f - 2.f / (__expf(2.f * x) + 1.f);
}

typedef float f4v __attribute__((ext_vector_type(4)));

template <bool LAST_ONLY>
__global__ __launch_bounds__(512, 2) void k_lstm6(const float* __restrict__ pre,
                                                  const float* __restrict__ Whh,
                                                  float* __restrict__ yout) {
  __shared__ float hbuf[2][128];
  const int tid = threadIdx.x;
  const int b = blockIdx.x;
  const int c4 = tid & 3;   // k-quarter
  const int u = tid >> 2;   // hidden unit 0..127

  // rotated float4 indices into h (R2-verified conflict-free pattern)
  int hidx[8];
#pragma unroll
  for (int j = 0; j < 8; j++) hidx[j] = c4 * 8 + (((u & 7) + 2 * c4 + j) & 7);

  // 32 named weight fragments: Wg_j = Whh[g*128+u][4*hidx[j] .. +3]
#define DECLW(g, j) \
  f4v W##g##_##j = *(const f4v*)(Whh + (size_t)((g)*128 + u) * 128 + hidx[j] * 4);
#define DECLW_ROW(g) \
  DECLW(g, 0) DECLW(g, 1) DECLW(g, 2) DECLW(g, 3) \
  DECLW(g, 4) DECLW(g, 5) DECLW(g, 6) DECLW(g, 7)
  DECLW_ROW(0) DECLW_ROW(1) DECLW_ROW(2) DECLW_ROW(3)
#undef DECLW_ROW
#undef DECLW

  if (tid < 128) hbuf[0][tid] = 0.f;
  float cs = 0.f;
  const float* preb = pre + (size_t)b * NT * NG + tid;  // tid == u*4 + c4 == P' column
  float pcur = preb[0];
  float* ybase = LAST_ONLY ? (yout + (size_t)b * NH + u)
                           : (yout + (size_t)b * NT * NH + u);
  __syncthreads();

#define PINW(g) \
  asm volatile("" : "+v"(W##g##_0), "+v"(W##g##_1), "+v"(W##g##_2), "+v"(W##g##_3)); \
  asm volatile("" : "+v"(W##g##_4), "+v"(W##g##_5), "+v"(W##g##_6), "+v"(W##g##_7));

#define FMA_J(j)                                                               \
  {                                                                            \
    f4v hv = hp[hidx[j]];                                                      \
    a0 = __builtin_elementwise_fma(W0_##j, hv, a0);                            \
    a1 = __builtin_elementwise_fma(W1_##j, hv, a1);                            \
    a2 = __builtin_elementwise_fma(W2_##j, hv, a2);                            \
    a3 = __builtin_elementwise_fma(W3_##j, hv, a3);                            \
  }

#define LSTM_STEP(CUR, NXT, T)                                                 \
  {                                                                            \
    int tn = (T) + 1; if (tn > NT - 1) tn = NT - 1;                            \
    float pnext = preb[(size_t)tn * NG];                                       \
    const f4v* hp = (const f4v*)&hbuf[CUR][0];                                 \
    f4v a0 = {0.f, 0.f, 0.f, 0.f}, a1 = a0, a2 = a0, a3 = a0;                  \
    FMA_J(0) FMA_J(1) FMA_J(2) FMA_J(3)                                        \
    FMA_J(4) FMA_J(5) FMA_J(6) FMA_J(7)                                        \
    float s0 = (a0.x + a0.y) + (a0.z + a0.w) + ((c4 == 0) ? pcur : 0.f);       \
    float s1 = (a1.x + a1.y) + (a1.z + a1.w) + ((c4 == 1) ? pcur : 0.f);       \
    float s2 = (a2.x + a2.y) + (a2.z + a2.w) + ((c4 == 2) ? pcur : 0.f);       \
    float s3 = (a3.x + a3.y) + (a3.z + a3.w) + ((c4 == 3) ? pcur : 0.f);       \
    s0 = dppadd<0xB1>(s0); s0 = dppadd<0x4E>(s0);                              \
    s1 = dppadd<0xB1>(s1); s1 = dppadd<0x4E>(s1);                              \
    s2 = dppadd<0xB1>(s2); s2 = dppadd<0x4E>(s2);                              \
    s3 = dppadd<0xB1>(s3); s3 = dppadd<0x4E>(s3);                              \
    float si = sigf(s0), sf = sigf(s1), tg = tanhf_fast(s2), so = sigf(s3);    \
    cs = sf * cs + si * tg;                                                    \
    float hnew = so * tanhf_fast(cs);                                          \
    if (c4 == 0) hbuf[NXT][u] = hnew;                                          \
    if (!LAST_ONLY) {                                                          \
      if (c4 == 1) ybase[(size_t)(T) * NH] = hnew;                             \
    } else if ((T) == NT - 1) {                                                \
      if (c4 == 1) *ybase = hnew;                                              \
    }                                                                          \
    pcur = pnext;                                                              \
    __syncthreads();                                                           \
  }

  for (int t = 0; t < NT; t += 2) {
    // In-loop pin on NAMED values: the asm may modify them, so the loads cannot be
    // rematerialized inside the loop; being scalars (not an aggregate) there is no
    // alloca to fall back to -> they must be carried in VGPRs across the loop.
    PINW(0) PINW(1) PINW(2) PINW(3)
    LSTM_STEP(0, 1, t);
    LSTM_STEP(1, 0, t + 1);
  }
#undef LSTM_STEP
#undef FMA_J
#undef PINW
}

// ---------------- host ----------------

extern "C" void kernel_launch(void* const* d_in, const int* in_sizes, int n_in,
                              void* d_out, int out_size, void* d_ws, size_t ws_size,
                              hipStream_t stream) {
  const float* x    = (const float*)d_in[0];   // [64,256,64] -> [16384,64]
  const float* dist = (const float*)d_in[1];   // [64,64]
  const int*   ei   = (const int*)d_in[2];     // [2, 524288]
  const float* W0   = (const float*)d_in[3];   // [4160,128]
  const float* b0   = (const float*)d_in[4];
  const float* W1   = (const float*)d_in[5];   // [128,128]
  const float* b1   = (const float*)d_in[6];
  const float* W2   = (const float*)d_in[7];
  const float* b2   = (const float*)d_in[8];
  const float* Wih0 = (const float*)d_in[9];   // [512,128]
  const float* Whh0 = (const float*)d_in[10];  // [512,128]
  const float* bih0 = (const float*)d_in[11];
  const float* bhh0 = (const float*)d_in[12];
  const float* Wih1 = (const float*)d_in[13];
  const float* Whh1 = (const float*)d_in[14];
  const float* bih1 = (const float*)d_in[15];
  const float* bhh1 = (const float*)d_in[16];
  const float* fcW  = (const float*)d_in[17];  // [768,128]
  const float* fcb  = (const float*)d_in[18];
  float* out = (float*)d_out;

  char* ws = (char*)d_ws;
  size_t off = 0;
  auto alloc = [&](size_t bytes) -> void* {
    void* p = ws + off;
    off += (bytes + 255) & ~(size_t)255;
    return p;
  };
  float* bufA     = (float*)alloc((size_t)NN * 128 * 4);
  float* bufB     = (float*)alloc((size_t)NN * 128 * 4);
  float* pre      = (float*)alloc((size_t)NN * 512 * 4);
  int2*  csr      = (int2*)alloc((size_t)NE * 8);
  int*   counts   = (int*)alloc((size_t)NN * 4);
  int*   fillc    = (int*)alloc((size_t)NN * 4);
  int*   rowstart = (int*)alloc((size_t)(NN + 1) * 4);
  float* dinv     = (float*)alloc((size_t)NN * 4);
  float* dvec     = (float*)alloc(128 * 4);
  float* hlast    = (float*)alloc(64 * 128 * 4);
  float* wt0      = (float*)alloc(128 * 64 * 4);
  float* wt1      = (float*)alloc(128 * 128 * 4);
  float* wt2      = (float*)alloc(128 * 128 * 4);
  (void)ws_size; (void)in_sizes; (void)n_in; (void)out_size;

  const int* srcIdx = ei;
  const int* dstIdx = ei + NE;

  hipMemsetAsync(counts, 0, (size_t)NN * 4, stream);
  hipMemsetAsync(fillc, 0, (size_t)NN * 4, stream);

  // weight transposes + distance vector
  k_transpose<<<(64 * 128 + 255) / 256, 256, 0, stream>>>(W0, wt0, 64, 128);
  k_transpose<<<(128 * 128 + 255) / 256, 256, 0, stream>>>(W1, wt1, 128, 128);
  k_transpose<<<(128 * 128 + 255) / 256, 256, 0, stream>>>(W2, wt2, 128, 128);
  k_dvec<<<128, 256, 0, stream>>>(dist, W0, dvec);

  // CSR build (reused by all 3 GCN layers)
  k_count<<<NE / 256, 256, 0, stream>>>(dstIdx, counts);
  k_scan<<<1, 1024, 0, stream>>>(counts, rowstart);
  k_dinv<<<NN / 256, 256, 0, stream>>>(counts, dinv);
  k_fill<<<NE / 256, 256, 0, stream>>>(srcIdx, dstIdx, rowstart, fillc, dinv, csr);

  // GCN layer 0: h0 = x @ W0a^T + dvec  (bias/relu happen after aggregation)
  dim3 gH(NN / 64, 128 / 64);
  k_gemm_abt<64, false><<<gH, 256, 0, stream>>>(x, wt0, dvec, nullptr, bufB, 128);
  k_agg<<<NN / 4, 256, 0, stream>>>(bufB, rowstart, csr, dinv, b0, bufA);
  // GCN layer 1
  k_gemm_abt<128, false><<<gH, 256, 0, stream>>>(bufA, wt1, nullptr, nullptr, bufB, 128);
  k_agg<<<NN / 4, 256, 0, stream>>>(bufB, rowstart, csr, dinv, b1, bufA);
  // GCN layer 2
  k_gemm_abt<128, false><<<gH, 256, 0, stream>>>(bufA, wt2, nullptr, nullptr, bufB, 128);
  k_agg<<<NN / 4, 256, 0, stream>>>(bufB, rowstart, csr, dinv, b2, bufA);

  // LSTM layer 0: pre (permuted) = feat @ Wih0^T + bih0 + bhh0 ; recurrence -> y1 (bufB)
  dim3 gP(NN / 64, 512 / 64);
  k_gemm_abt<128, false, true><<<gP, 256, 0, stream>>>(bufA, Wih0, bih0, bhh0, pre, 512);
  k_lstm6<false><<<64, 512, 0, stream>>>(pre, Whh0, bufB);
  // LSTM layer 1
  k_gemm_abt<128, false, true><<<gP, 256, 0, stream>>>(bufB, Wih1, bih1, bhh1, pre, 512);
  k_lstm6<true><<<64, 512, 0, stream>>>(pre, Whh1, hlast);

  // FC: out[64,768] = hlast @ fcW^T + fcb
  dim3 gF(1, NOUT / 64);
  k_gemm_abt<128, false><<<gF, 256, 0, stream>>>(hlast, fcW, fcb, nullptr, out, NOUT);
}

// Round 7
// 887.973 us; speedup vs baseline: 1.2462x; 1.0358x over previous
//
#include <hip/hip_runtime.h>
#include <hip/hip_bf16.h>
#include <cstdint>
#include <cstddef>

// Problem constants
#define NB 64      // batch
#define NT 256     // time steps
#define NL 64      // links
#define NH 128     // hidden
#define NN 16384   // nodes = NB*NT
#define NE 524288  // edges
#define NG 512     // 4*NH gates
#define NOUT 768   // 12*NL

// ---------------- small prep kernels ----------------

// Wt[n][k] = W[k][n], W is [K, Nout] row-major
__global__ __launch_bounds__(256) void k_transpose(const float* __restrict__ W,
                                                   float* __restrict__ Wt,
                                                   int K, int Nout) {
  int i = blockIdx.x * 256 + threadIdx.x;
  if (i < K * Nout) {
    int k = i / Nout, n = i % Nout;
    Wt[n * K + k] = W[i];
  }
}

// dvec[j] = sum_m dist[m] * W0[(64+m)*128 + j]   (128 blocks, one per j)
__global__ __launch_bounds__(256) void k_dvec(const float* __restrict__ dist,
                                              const float* __restrict__ W0,
                                              float* __restrict__ dvec) {
  __shared__ float red[256];
  int j = blockIdx.x;
  int t = threadIdx.x;
  float acc = 0.f;
  for (int m = t; m < 4096; m += 256)
    acc += dist[m] * W0[(size_t)(64 + m) * 128 + j];
  red[t] = acc;
  __syncthreads();
  for (int off = 128; off > 0; off >>= 1) {
    if (t < off) red[t] += red[t + off];
    __syncthreads();
  }
  if (t == 0) dvec[j] = red[0];
}

__global__ __launch_bounds__(256) void k_count(const int* __restrict__ dst,
                                               int* __restrict__ counts) {
  int i = blockIdx.x * 256 + threadIdx.x;
  atomicAdd(&counts[dst[i]], 1);
}

__global__ __launch_bounds__(256) void k_dinv(const int* __restrict__ counts,
                                              float* __restrict__ dinv) {
  int n = blockIdx.x * 256 + threadIdx.x;
  dinv[n] = rsqrtf((float)counts[n] + 1.0f);
}

// exclusive scan of counts[16384] -> rowstart[16385]; single block of 1024
__global__ __launch_bounds__(1024) void k_scan(const int* __restrict__ counts,
                                               int* __restrict__ rowstart) {
  __shared__ int part[1024];
  int t = threadIdx.x;
  int base = t * 16;
  int local[16];
  int s = 0;
#pragma unroll
  for (int i = 0; i < 16; i++) { local[i] = s; s += counts[base + i]; }
  part[t] = s;
  __syncthreads();
  for (int off = 1; off < 1024; off <<= 1) {
    int v = (t >= off) ? part[t - off] : 0;
    __syncthreads();
    part[t] += v;
    __syncthreads();
  }
  int prefix = (t == 0) ? 0 : part[t - 1];
#pragma unroll
  for (int i = 0; i < 16; i++) rowstart[base + i] = prefix + local[i];
  if (t == 1023) rowstart[16384] = part[1023];
}

__global__ __launch_bounds__(256) void k_fill(const int* __restrict__ src,
                                              const int* __restrict__ dst,
                                              const int* __restrict__ rowstart,
                                              int* __restrict__ fill,
                                              const float* __restrict__ dinv,
                                              int2* __restrict__ csr) {
  int e = blockIdx.x * 256 + threadIdx.x;
  int sN = src[e], dN = dst[e];
  int pos = rowstart[dN] + atomicAdd(&fill[dN], 1);
  csr[pos] = make_int2(sN, __float_as_int(dinv[sN] * dinv[dN]));
}

// ---------------- GEMM: C[M,Nn] = A[M,K] * B[Nn,K]^T (+bias0+bias1) ----------------
// grid (M/64, Nn/64), block 256. K = 64 or 128.
// PERMC: store col' = (col&127)*4 + (col>>7)  (gate-interleaved layout for LSTM pre)
template <int K, bool RELU, bool PERMC = false>
__global__ __launch_bounds__(256) void k_gemm_abt(const float* __restrict__ A,
                                                  const float* __restrict__ Bm,
                                                  const float* __restrict__ bias0,
                                                  const float* __restrict__ bias1,
                                                  float* __restrict__ C, int Nn) {
  __shared__ float As[64][K + 1];
  __shared__ float Bs[64][K + 1];
  const int tid = threadIdx.x;
  const int bm = blockIdx.x, bn = blockIdx.y;
  const int VPR = K / 4;  // float4 per row
  for (int i = tid; i < 64 * VPR; i += 256) {
    int r = i / VPR, v = (i % VPR) * 4;
    float4 q = *(const float4*)(A + (size_t)(bm * 64 + r) * K + v);
    As[r][v] = q.x; As[r][v + 1] = q.y; As[r][v + 2] = q.z; As[r][v + 3] = q.w;
  }
  for (int i = tid; i < 64 * VPR; i += 256) {
    int r = i / VPR, v = (i % VPR) * 4;
    float4 q = *(const float4*)(Bm + (size_t)(bn * 64 + r) * K + v);
    Bs[r][v] = q.x; Bs[r][v + 1] = q.y; Bs[r][v + 2] = q.z; Bs[r][v + 3] = q.w;
  }
  __syncthreads();
  const int tr = (tid >> 4) << 2;   // output rows tr..tr+3
  const int tc = (tid & 15) << 2;   // output cols tc..tc+3
  float acc[4][4] = {};
#pragma unroll 4
  for (int k = 0; k < K; k++) {
    float a0 = As[tr + 0][k], a1 = As[tr + 1][k], a2 = As[tr + 2][k], a3 = As[tr + 3][k];
    float b0 = Bs[tc + 0][k], b1 = Bs[tc + 1][k], b2 = Bs[tc + 2][k], b3 = Bs[tc + 3][k];
    acc[0][0] += a0 * b0; acc[0][1] += a0 * b1; acc[0][2] += a0 * b2; acc[0][3] += a0 * b3;
    acc[1][0] += a1 * b0; acc[1][1] += a1 * b1; acc[1][2] += a1 * b2; acc[1][3] += a1 * b3;
    acc[2][0] += a2 * b0; acc[2][1] += a2 * b1; acc[2][2] += a2 * b2; acc[2][3] += a2 * b3;
    acc[3][0] += a3 * b0; acc[3][1] += a3 * b1; acc[3][2] += a3 * b2; acc[3][3] += a3 * b3;
  }
#pragma unroll
  for (int i2 = 0; i2 < 4; i2++) {
    int row = bm * 64 + tr + i2;
#pragma unroll
    for (int j2 = 0; j2 < 4; j2++) {
      int col = bn * 64 + tc + j2;
      float v = acc[i2][j2];
      if (bias0) v += bias0[col];
      if (bias1) v += bias1[col];
      if (RELU) v = fmaxf(v, 0.f);
      int colw = PERMC ? ((col & 127) * 4 + (col >> 7)) : col;
      C[(size_t)row * Nn + colw] = v;
    }
  }
}

// ---------------- GCN aggregation (float2 lanes, packed CSR) ----------------
__global__ __launch_bounds__(256) void k_agg(const float* __restrict__ h,
                                             const int* __restrict__ rowstart,
                                             const int2* __restrict__ csr,
                                             const float* __restrict__ dinv,
                                             const float* __restrict__ bias,
                                             float* __restrict__ out) {
  int node = blockIdx.x * 4 + (threadIdx.x >> 6);
  int lane = threadIdx.x & 63;
  int s = rowstart[node], e = rowstart[node + 1];
  const float2* h2 = (const float2*)h;
  float ax = 0.f, ay = 0.f;
  int p = s;
  for (; p + 1 < e; p += 2) {
    int2 pk0 = csr[p];
    int2 pk1 = csr[p + 1];
    float2 hv0 = h2[(size_t)pk0.x * 64 + lane];
    float2 hv1 = h2[(size_t)pk1.x * 64 + lane];
    float w0 = __int_as_float(pk0.y);
    float w1 = __int_as_float(pk1.y);
    ax = fmaf(hv0.x, w0, ax); ay = fmaf(hv0.y, w0, ay);
    ax = fmaf(hv1.x, w1, ax); ay = fmaf(hv1.y, w1, ay);
  }
  if (p < e) {
    int2 pk0 = csr[p];
    float2 hv0 = h2[(size_t)pk0.x * 64 + lane];
    float w0 = __int_as_float(pk0.y);
    ax = fmaf(hv0.x, w0, ax); ay = fmaf(hv0.y, w0, ay);
  }
  float di = dinv[node];
  float sw = di * di;
  float2 hs = h2[(size_t)node * 64 + lane];
  float2 bv = ((const float2*)bias)[lane];
  ax = fmaf(hs.x, sw, ax) + bv.x;
  ay = fmaf(hs.y, sw, ay) + bv.y;
  float2 o;
  o.x = fmaxf(ax, 0.f);
  o.y = fmaxf(ay, 0.f);
  ((float2*)out)[(size_t)node * 64 + lane] = o;
}

// ---------------- LSTM recurrence v7: quad-per-unit, waves_per_eu(2,2) ----------
// Identical structure to v6 (named weight registers + in-loop pin). ONE change:
// amdgpu_waves_per_eu(2,2) pins the backend's occupancy TARGET to exactly 2
// waves/EU. __launch_bounds__'s 2nd arg only sets the minimum (a VGPR cap of
// 256); the allocator's heuristic was still targeting higher occupancy
// (52-88 VGPRs across R2-R6) and satisfying the pins via scratch reload --
// which put the kernel exactly on the per-CU L2-link bandwidth floor
// (~256KB weights/step/CU ≈ 850ns/step ≈ the observed 895ns/step).
// With max=2 the heuristic has no reason to shrink below the 256-VGPR budget,
// so the 128 weight VGPRs + ~60 temps can be held resident.

template <int CTRL>
__device__ __forceinline__ float dppadd(float x) {
  int r = __builtin_amdgcn_update_dpp(0, __float_as_int(x), CTRL, 0xF, 0xF, true);
  return x + __int_as_float(r);
}
// quad_perm[1,0,3,2] = 0xB1 (xor1), quad_perm[2,3,0,1] = 0x4E (xor2)

__device__ __forceinline__ float sigf(float x) {
  return 1.f / (1.f + __expf(-x));
}
__device__ __forceinline__ float tanhf_fast(float x) {
  return 1.f - 2.f / (__expf(2.f * x) + 1.f);
}

typedef float f4v __attribute__((ext_vector_type(4)));

template <bool LAST_ONLY>
__global__ __launch_bounds__(512)
__attribute__((amdgpu_waves_per_eu(2, 2)))
void k_lstm7(const float* __restrict__ pre,
             const float* __restrict__ Whh,
             float* __restrict__ yout) {
  __shared__ float hbuf[2][128];
  const int tid = threadIdx.x;
  const int b = blockIdx.x;
  const int c4 = tid & 3;   // k-quarter
  const int u = tid >> 2;   // hidden unit 0..127

  // rotated float4 indices into h (R2-verified conflict-free pattern)
  int hidx[8];
#pragma unroll
  for (int j = 0; j < 8; j++) hidx[j] = c4 * 8 + (((u & 7) + 2 * c4 + j) & 7);

  // 32 named weight fragments: Wg_j = Whh[g*128+u][4*hidx[j] .. +3]
#define DECLW(g, j) \
  f4v W##g##_##j = *(const f4v*)(Whh + (size_t)((g)*128 + u) * 128 + hidx[j] * 4);
#define DECLW_ROW(g) \
  DECLW(g, 0) DECLW(g, 1) DECLW(g, 2) DECLW(g, 3) \
  DECLW(g, 4) DECLW(g, 5) DECLW(g, 6) DECLW(g, 7)
  DECLW_ROW(0) DECLW_ROW(1) DECLW_ROW(2) DECLW_ROW(3)
#undef DECLW_ROW
#undef DECLW

  if (tid < 128) hbuf[0][tid] = 0.f;
  float cs = 0.f;
  const float* preb = pre + (size_t)b * NT * NG + tid;  // tid == u*4 + c4 == P' column
  float pcur = preb[0];
  float* ybase = LAST_ONLY ? (yout + (size_t)b * NH + u)
                           : (yout + (size_t)b * NT * NH + u);
  __syncthreads();

#define PINW(g) \
  asm volatile("" : "+v"(W##g##_0), "+v"(W##g##_1), "+v"(W##g##_2), "+v"(W##g##_3)); \
  asm volatile("" : "+v"(W##g##_4), "+v"(W##g##_5), "+v"(W##g##_6), "+v"(W##g##_7));

#define FMA_J(j)                                                               \
  {                                                                            \
    f4v hv = hp[hidx[j]];                                                      \
    a0 = __builtin_elementwise_fma(W0_##j, hv, a0);                            \
    a1 = __builtin_elementwise_fma(W1_##j, hv, a1);                            \
    a2 = __builtin_elementwise_fma(W2_##j, hv, a2);                            \
    a3 = __builtin_elementwise_fma(W3_##j, hv, a3);                            \
  }

#define LSTM_STEP(CUR, NXT, T)                                                 \
  {                                                                            \
    int tn = (T) + 1; if (tn > NT - 1) tn = NT - 1;                            \
    float pnext = preb[(size_t)tn * NG];                                       \
    const f4v* hp = (const f4v*)&hbuf[CUR][0];                                 \
    f4v a0 = {0.f, 0.f, 0.f, 0.f}, a1 = a0, a2 = a0, a3 = a0;                  \
    FMA_J(0) FMA_J(1) FMA_J(2) FMA_J(3)                                        \
    FMA_J(4) FMA_J(5) FMA_J(6) FMA_J(7)                                        \
    float s0 = (a0.x + a0.y) + (a0.z + a0.w) + ((c4 == 0) ? pcur : 0.f);       \
    float s1 = (a1.x + a1.y) + (a1.z + a1.w) + ((c4 == 1) ? pcur : 0.f);       \
    float s2 = (a2.x + a2.y) + (a2.z + a2.w) + ((c4 == 2) ? pcur : 0.f);       \
    float s3 = (a3.x + a3.y) + (a3.z + a3.w) + ((c4 == 3) ? pcur : 0.f);       \
    s0 = dppadd<0xB1>(s0); s0 = dppadd<0x4E>(s0);                              \
    s1 = dppadd<0xB1>(s1); s1 = dppadd<0x4E>(s1);                              \
    s2 = dppadd<0xB1>(s2); s2 = dppadd<0x4E>(s2);                              \
    s3 = dppadd<0xB1>(s3); s3 = dppadd<0x4E>(s3);                              \
    float si = sigf(s0), sf = sigf(s1), tg = tanhf_fast(s2), so = sigf(s3);    \
    cs = sf * cs + si * tg;                                                    \
    float hnew = so * tanhf_fast(cs);                                          \
    if (c4 == 0) hbuf[NXT][u] = hnew;                                          \
    if (!LAST_ONLY) {                                                          \
      if (c4 == 1) ybase[(size_t)(T) * NH] = hnew;                             \
    } else if ((T) == NT - 1) {                                                \
      if (c4 == 1) *ybase = hnew;                                              \
    }                                                                          \
    pcur = pnext;                                                              \
    __syncthreads();                                                           \
  }

  for (int t = 0; t < NT; t += 2) {
    // In-loop pin on NAMED values: the asm may modify them, so the loads cannot
    // be rematerialized inside the loop; with waves_per_eu(2,2) the allocator
    // has a 256-VGPR budget and no occupancy incentive to spill them.
    PINW(0) PINW(1) PINW(2) PINW(3)
    LSTM_STEP(0, 1, t);
    LSTM_STEP(1, 0, t + 1);
  }
#undef LSTM_STEP
#undef FMA_J
#undef PINW
}

// ---------------- host ----------------

extern "C" void kernel_launch(void* const* d_in, const int* in_sizes, int n_in,
                              void* d_out, int out_size, void* d_ws, size_t ws_size,
                              hipStream_t stream) {
  const float* x    = (const float*)d_in[0];   // [64,256,64] -> [16384,64]
  const float* dist = (const float*)d_in[1];   // [64,64]
  const int*   ei   = (const int*)d_in[2];     // [2, 524288]
  const float* W0   = (const float*)d_in[3];   // [4160,128]
  const float* b0   = (const float*)d_in[4];
  const float* W1   = (const float*)d_in[5];   // [128,128]
  const float* b1   = (const float*)d_in[6];
  const float* W2   = (const float*)d_in[7];
  const float* b2   = (const float*)d_in[8];
  const float* Wih0 = (const float*)d_in[9];   // [512,128]
  const float* Whh0 = (const float*)d_in[10];  // [512,128]
  const float* bih0 = (const float*)d_in[11];
  const float* bhh0 = (const float*)d_in[12];
  const float* Wih1 = (const float*)d_in[13];
  const float* Whh1 = (const float*)d_in[14];
  const float* bih1 = (const float*)d_in[15];
  const float* bhh1 = (const float*)d_in[16];
  const float* fcW  = (const float*)d_in[17];  // [768,128]
  const float* fcb  = (const float*)d_in[18];
  float* out = (float*)d_out;

  char* ws = (char*)d_ws;
  size_t off = 0;
  auto alloc = [&](size_t bytes) -> void* {
    void* p = ws + off;
    off += (bytes + 255) & ~(size_t)255;
    return p;
  };
  float* bufA     = (float*)alloc((size_t)NN * 128 * 4);
  float* bufB     = (float*)alloc((size_t)NN * 128 * 4);
  float* pre      = (float*)alloc((size_t)NN * 512 * 4);
  int2*  csr      = (int2*)alloc((size_t)NE * 8);
  int*   counts   = (int*)alloc((size_t)NN * 4);
  int*   fillc    = (int*)alloc((size_t)NN * 4);
  int*   rowstart = (int*)alloc((size_t)(NN + 1) * 4);
  float* dinv     = (float*)alloc((size_t)NN * 4);
  float* dvec     = (float*)alloc(128 * 4);
  float* hlast    = (float*)alloc(64 * 128 * 4);
  float* wt0      = (float*)alloc(128 * 64 * 4);
  float* wt1      = (float*)alloc(128 * 128 * 4);
  float* wt2      = (float*)alloc(128 * 128 * 4);
  (void)ws_size; (void)in_sizes; (void)n_in; (void)out_size;

  const int* srcIdx = ei;
  const int* dstIdx = ei + NE;

  hipMemsetAsync(counts, 0, (size_t)NN * 4, stream);
  hipMemsetAsync(fillc, 0, (size_t)NN * 4, stream);

  // weight transposes + distance vector
  k_transpose<<<(64 * 128 + 255) / 256, 256, 0, stream>>>(W0, wt0, 64, 128);
  k_transpose<<<(128 * 128 + 255) / 256, 256, 0, stream>>>(W1, wt1, 128, 128);
  k_transpose<<<(128 * 128 + 255) / 256, 256, 0, stream>>>(W2, wt2, 128, 128);
  k_dvec<<<128, 256, 0, stream>>>(dist, W0, dvec);

  // CSR build (reused by all 3 GCN layers)
  k_count<<<NE / 256, 256, 0, stream>>>(dstIdx, counts);
  k_scan<<<1, 1024, 0, stream>>>(counts, rowstart);
  k_dinv<<<NN / 256, 256, 0, stream>>>(counts, dinv);
  k_fill<<<NE / 256, 256, 0, stream>>>(srcIdx, dstIdx, rowstart, fillc, dinv, csr);

  // GCN layer 0: h0 = x @ W0a^T + dvec  (bias/relu happen after aggregation)
  dim3 gH(NN / 64, 128 / 64);
  k_gemm_abt<64, false><<<gH, 256, 0, stream>>>(x, wt0, dvec, nullptr, bufB, 128);
  k_agg<<<NN / 4, 256, 0, stream>>>(bufB, rowstart, csr, dinv, b0, bufA);
  // GCN layer 1
  k_gemm_abt<128, false><<<gH, 256, 0, stream>>>(bufA, wt1, nullptr, nullptr, bufB, 128);
  k_agg<<<NN / 4, 256, 0, stream>>>(bufB, rowstart, csr, dinv, b1, bufA);
  // GCN layer 2
  k_gemm_abt<128, false><<<gH, 256, 0, stream>>>(bufA, wt2, nullptr, nullptr, bufB, 128);
  k_agg<<<NN / 4, 256, 0, stream>>>(bufB, rowstart, csr, dinv, b2, bufA);

  // LSTM layer 0: pre (permuted) = feat @ Wih0^T + bih0 + bhh0 ; recurrence -> y1 (bufB)
  dim3 gP(NN / 64, 512 / 64);
  k_gemm_abt<128, false, true><<<gP, 256, 0, stream>>>(bufA, Wih0, bih0, bhh0, pre, 512);
  k_lstm7<false><<<64, 512, 0, stream>>>(pre, Whh0, bufB);
  // LSTM layer 1
  k_gemm_abt<128, false, true><<<gP, 256, 0, stream>>>(bufB, Wih1, bih1, bhh1, pre, 512);
  k_lstm7<true><<<64, 512, 0, stream>>>(pre, Whh1, hlast);

  // FC: out[64,768] = hlast @ fcW^T + fcb
  dim3 gF(1, NOUT / 64);
  k_gemm_abt<128, false><<<gF, 256, 0, stream>>>(hlast, fcW, fcb, nullptr, out, NOUT);
}